// Round 6
// baseline (1503.677 us; speedup 1.0000x reference)
//
#include <hip/hip_runtime.h>
#include <math.h>

#define L_DEC 2306
#define MPAD 2560      // 10*256, decoder rows padded
#define T_FINE 2304    // 9*256, exact

typedef float f32x4 __attribute__((ext_vector_type(4)));
typedef __bf16 bf16x8 __attribute__((ext_vector_type(8)));
typedef unsigned short u16;
typedef unsigned short us4 __attribute__((ext_vector_type(4)));
typedef unsigned short us8 __attribute__((ext_vector_type(8)));

#define GLOAD16(g, l) __builtin_amdgcn_global_load_lds( \
    (const __attribute__((address_space(1))) unsigned int*)(g), \
    (__attribute__((address_space(3))) unsigned int*)(l), 16, 0, 0)

__device__ __forceinline__ u16 f2bf(float f) {
  unsigned u = __float_as_uint(f);
  u += 0x7fffu + ((u >> 16) & 1u);   // RNE
  return (u16)(u >> 16);
}

__device__ __forceinline__ int fix_csp(const int* p) {
  int c = p[0];
  if ((unsigned)c <= 4u) return c;
  float f = __uint_as_float((unsigned)c);
  int c2 = (int)f;
  return ((unsigned)c2 <= 4u) ? c2 : 4;
}

// XCD-aware bijective block swizzle (m204) over x*y tile space.
__device__ __forceinline__ void xcd_map(int gx, int gy, int& bm, int& bn, int TS) {
  const int nwg = gx * gy;
  const int orig = blockIdx.y * gx + blockIdx.x;
  const int q8 = nwg >> 3, r8 = nwg & 7;
  const int xcd = orig & 7, idx8 = orig >> 3;
  const int wg = (xcd < r8 ? xcd * (q8 + 1) : r8 * (q8 + 1) + (xcd - r8) * q8) + idx8;
  bm = (wg / gx) * TS;
  bn = (wg % gx) * TS;
}

// ================= 256^2, BK=64, double-buffered, dynamic 128KB LDS =====================
template<int EPI>
__global__ __launch_bounds__(512, 1) void k_gemm3(const u16* __restrict__ A,
                                                  const u16* __restrict__ B,
                                                  float* __restrict__ C,
                                                  int N, int K, int Mstore)
{
  extern __shared__ u16 lds[];   // [2 buf][A:16384 | B:16384] u16  (= 128 KB)
  const int tid = threadIdx.x;
  int bm, bn; xcd_map(gridDim.x, gridDim.y, bm, bn, 256);
  const int w = tid >> 6, lane = tid & 63;
  const int wm = (w >> 2) * 128, wn = (w & 3) * 64;
  const int lr = lane & 15, kh = lane >> 4;

#define STAGE3(buf, kt) do {                                                   \
    u16* lA = lds + (buf) * 32768;                                             \
    u16* lB = lA + 16384;                                                      \
    _Pragma("unroll")                                                          \
    for (int p = 0; p < 4; ++p) {                                              \
      int e = p * 512 + tid;                                                   \
      int row = e >> 3;                                                        \
      int kc = ((e & 7) ^ (row & 7)) * 8;   /* pre-swizzled global k-offset */ \
      GLOAD16(A + (size_t)(bm + row) * K + (size_t)(kt) * 64 + kc, lA + e * 8);\
      GLOAD16(B + (size_t)(bn + row) * K + (size_t)(kt) * 64 + kc, lB + e * 8);\
    }                                                                          \
  } while (0)

  f32x4 acc[8][4] = {};
  const int nt = K >> 6;
  STAGE3(0, 0);
  __syncthreads();
  int cur = 0;
  for (int t = 0; t < nt; ++t) {
    if (t + 1 < nt) STAGE3(cur ^ 1, t + 1);
    const u16* pA = lds + cur * 32768;
    const u16* pB = pA + 16384;
    const int xr = (lr & 7) << 3;           // row-XOR for swizzled ds_read
#pragma unroll
    for (int kt2 = 0; kt2 < 2; ++kt2) {
      bf16x8 af[8], bf[4];
#pragma unroll
      for (int m = 0; m < 8; ++m)
        af[m] = *(const bf16x8*)&pA[(wm + m * 16 + lr) * 64 + ((kt2 * 32 + kh * 8) ^ xr)];
#pragma unroll
      for (int n = 0; n < 4; ++n)
        bf[n] = *(const bf16x8*)&pB[(wn + n * 16 + lr) * 64 + ((kt2 * 32 + kh * 8) ^ xr)];
#pragma unroll
      for (int m = 0; m < 8; ++m)
#pragma unroll
        for (int n = 0; n < 4; ++n)
          acc[m][n] = __builtin_amdgcn_mfma_f32_16x16x32_bf16(af[m], bf[n], acc[m][n], 0, 0, 0);
    }
    __syncthreads();
    cur ^= 1;
  }
#undef STAGE3

#pragma unroll
  for (int m = 0; m < 8; ++m) {
    int gr0 = bm + wm + m * 16 + kh * 4;
#pragma unroll
    for (int n = 0; n < 4; ++n) {
      int gc = bn + wn + n * 16 + lr;
#pragma unroll
      for (int r = 0; r < 4; ++r) {
        int gr = gr0 + r;
        if (gr < Mstore) C[(size_t)gr * N + gc] = acc[m][n][r];
      }
    }
  }
}

// ================= 256^2 2-phase BK=32 (static 64KB LDS) — head fallback ================
template<int EPI>
__global__ __launch_bounds__(512, 1) void k_gemm2(const u16* __restrict__ A,
                                                  const u16* __restrict__ B,
                                                  float* __restrict__ C,
                                                  u16* __restrict__ Cb,
                                                  int N, int K, int Mstore)
{
  __shared__ u16 As[2][8192];
  __shared__ u16 Bs[2][8192];
  const int tid = threadIdx.x;
  int bm, bn; xcd_map(gridDim.x, gridDim.y, bm, bn, 256);
  const int w = tid >> 6, lane = tid & 63;
  const int wm = (w >> 2) * 128, wn = (w & 3) * 64;
  const int lr = lane & 15, kh = lane >> 4;
  const int r0 = tid >> 2;
  const int ksrc = 8 * ((tid & 3) ^ ((tid >> 3) & 3));
  const u16* ga = A + (size_t)(bm + r0) * K + ksrc;
  const u16* gb = B + (size_t)(bn + r0) * K + ksrc;
  const size_t rstep = (size_t)128 * K;
  const int cola = (kh * 8) ^ (((lr >> 1) & 3) << 3);

#define STAGE2(buf, kt) do {                                   \
    const u16* gA = ga + (size_t)(kt) * 32;                    \
    const u16* gB = gb + (size_t)(kt) * 32;                    \
    GLOAD16(gA,         &As[buf][tid * 8]);                    \
    GLOAD16(gA + rstep, &As[buf][tid * 8 + 4096]);             \
    GLOAD16(gB,         &Bs[buf][tid * 8]);                    \
    GLOAD16(gB + rstep, &Bs[buf][tid * 8 + 4096]);             \
  } while (0)

  f32x4 acc[8][4] = {};
  const int nt = K >> 5;
  STAGE2(0, 0);
  __syncthreads();
  int cur = 0;
  for (int t = 0; t < nt; ++t) {
    if (t + 1 < nt) STAGE2(cur ^ 1, t + 1);
    bf16x8 af[8], bf[4];
#pragma unroll
    for (int m = 0; m < 8; ++m)
      af[m] = *(const bf16x8*)&As[cur][(wm + m * 16 + lr) * 32 + cola];
#pragma unroll
    for (int n = 0; n < 4; ++n)
      bf[n] = *(const bf16x8*)&Bs[cur][(wn + n * 16 + lr) * 32 + cola];
#pragma unroll
    for (int m = 0; m < 8; ++m)
#pragma unroll
      for (int n = 0; n < 4; ++n)
        acc[m][n] = __builtin_amdgcn_mfma_f32_16x16x32_bf16(af[m], bf[n], acc[m][n], 0, 0, 0);
    __syncthreads();
    cur ^= 1;
  }
#undef STAGE2

#pragma unroll
  for (int m = 0; m < 8; ++m) {
    int gr0 = bm + wm + m * 16 + kh * 4;
#pragma unroll
    for (int n = 0; n < 4; ++n) {
      int gc = bn + wn + n * 16 + lr;
#pragma unroll
      for (int r = 0; r < 4; ++r) {
        int gr = gr0 + r;
        if (gr < Mstore) C[(size_t)gr * N + gc] = acc[m][n][r];
      }
    }
  }
}

// ================= 128^2 MFMA GEMM (m97 + T2 swizzle + XCD swizzle) =====================
// EPI=0: store into split-K plane z.  EPI=1: C += acc.  EPI=2: silu-fused g|u -> Cb bf16.
template<int EPI>
__global__ __launch_bounds__(256) void k_gemm_bt(const u16* __restrict__ A,
                                                 const u16* __restrict__ B,
                                                 float* __restrict__ C,
                                                 u16* __restrict__ Cb,
                                                 int N, int K, int Mstore, int kchunk)
{
  __shared__ u16 As[4096];
  __shared__ u16 Bs[4096];
  const int tid = threadIdx.x;
  int bm, bn; xcd_map(gridDim.x, gridDim.y, bm, bn, 128);
  const int k0 = blockIdx.z * kchunk;
  const int w = tid >> 6, lane = tid & 63;
  const int wm = (w >> 1) * 64, wn = (w & 1) * 64;
  const int lr = lane & 15, kh = lane >> 4;
  const int r0 = tid >> 2;
  const int ksrc = 8 * ((tid & 3) ^ ((tid >> 3) & 3));
  const int cola = (kh * 8) ^ (((lr >> 1) & 3) << 3);

  const u16* ga = A + (size_t)(bm + r0) * K + k0 + ksrc;
  const u16* gb = B + (size_t)(bn + r0) * K + k0 + ksrc;
  u16* la = &As[tid * 8];
  u16* lb = &Bs[tid * 8];
  const size_t rstep = (size_t)64 * K;

  f32x4 acc[4][4] = {};
  for (int kk = 0; kk < kchunk; kk += 32) {
    GLOAD16(ga, la); GLOAD16(ga + rstep, la + 2048);
    GLOAD16(gb, lb); GLOAD16(gb + rstep, lb + 2048);
    ga += 32; gb += 32;
    __syncthreads();
    bf16x8 af[4], bfr[4];
#pragma unroll
    for (int m = 0; m < 4; ++m)
      af[m] = *(const bf16x8*)&As[(wm + m * 16 + lr) * 32 + cola];
#pragma unroll
    for (int n = 0; n < 4; ++n)
      bfr[n] = *(const bf16x8*)&Bs[(wn + n * 16 + lr) * 32 + cola];
#pragma unroll
    for (int m = 0; m < 4; ++m)
#pragma unroll
      for (int n = 0; n < 4; ++n)
        acc[m][n] = __builtin_amdgcn_mfma_f32_16x16x32_bf16(af[m], bfr[n], acc[m][n], 0, 0, 0);
    __syncthreads();
  }

  float* Cz = (EPI == 0) ? C + (size_t)blockIdx.z * Mstore * N : C;
  const int N2 = N >> 1;
#pragma unroll
  for (int m = 0; m < 4; ++m) {
    int gr0 = bm + wm + m * 16 + kh * 4;
#pragma unroll
    for (int n = 0; n < 4; ++n) {
      int gc = bn + wn + n * 16 + lr;
#pragma unroll
      for (int r = 0; r < 4; ++r) {
        int gr = gr0 + r;
        if (EPI == 2) {
          float x = acc[m][n][r];
          float px = __shfl_xor(x, 1);          // partner u (all lanes execute)
          if (!(lr & 1) && gr < Mstore) {
            float s = x / (1.f + expf(-x)) * px;
            Cb[(size_t)gr * N2 + (gc >> 1)] = f2bf(s);
          }
        } else if (gr < Mstore) {
          size_t off = (size_t)gr * N + gc;
          if (EPI == 0) Cz[off] = acc[m][n][r];
          else          C[off] += acc[m][n][r];
        }
      }
    }
  }
}

// Head fallback when ws can't hold bf16 w_out.
__global__ __launch_bounds__(256) void k_gemm_hf(const u16* __restrict__ A,
                                                 const float* __restrict__ B,
                                                 float* __restrict__ C,
                                                 int N, int K, int Mstore)
{
  __shared__ u16 As[4096];
  __shared__ u16 Bs[4096];
  const int tid = threadIdx.x;
  const int bm = blockIdx.y * 128, bn = blockIdx.x * 128;
  const int w = tid >> 6, lane = tid & 63;
  const int wm = (w >> 1) * 64, wn = (w & 1) * 64;
  const int lr = lane & 15, kh = lane >> 4;
  const int r0 = tid >> 2;
  const int ksrc = 8 * ((tid & 3) ^ ((tid >> 3) & 3));
  const int cola = (kh * 8) ^ (((lr >> 1) & 3) << 3);
  const u16* ga = A + (size_t)(bm + r0) * K + ksrc;
  u16* la = &As[tid * 8];
  const size_t rstep = (size_t)64 * K;

  f32x4 acc[4][4] = {};
  for (int kk = 0; kk < K; kk += 32) {
    GLOAD16(ga, la); GLOAD16(ga + rstep, la + 2048);
    ga += 32;
#pragma unroll
    for (int p = 0; p < 4; ++p) {
      int e = tid + p * 256;
      int row = e >> 3, kc = (e & 7) * 4;
      int kcs = kc ^ (((row >> 1) & 3) << 3);
      float4 v = *(const float4*)(B + (size_t)(bn + row) * K + kk + kc);
      us4 pk; pk[0] = f2bf(v.x); pk[1] = f2bf(v.y); pk[2] = f2bf(v.z); pk[3] = f2bf(v.w);
      *(us4*)&Bs[row * 32 + kcs] = pk;
    }
    __syncthreads();
    bf16x8 af[4], bfr[4];
#pragma unroll
    for (int m = 0; m < 4; ++m)
      af[m] = *(const bf16x8*)&As[(wm + m * 16 + lr) * 32 + cola];
#pragma unroll
    for (int n = 0; n < 4; ++n)
      bfr[n] = *(const bf16x8*)&Bs[(wn + n * 16 + lr) * 32 + cola];
#pragma unroll
    for (int m = 0; m < 4; ++m)
#pragma unroll
      for (int n = 0; n < 4; ++n)
        acc[m][n] = __builtin_amdgcn_mfma_f32_16x16x32_bf16(af[m], bfr[n], acc[m][n], 0, 0, 0);
    __syncthreads();
  }
#pragma unroll
  for (int m = 0; m < 4; ++m) {
    int gr0 = bm + wm + m * 16 + kh * 4;
#pragma unroll
    for (int n = 0; n < 4; ++n) {
      int gc = bn + wn + n * 16 + lr;
#pragma unroll
      for (int r = 0; r < 4; ++r) {
        int gr = gr0 + r;
        if (gr < Mstore) C[(size_t)gr * N + gc] = acc[m][n][r];
      }
    }
  }
}

// ---------------- weight transpose-convert: W[K,N] f32 -> Wt[(n*rs+ro)][K] bf16 --------
__global__ __launch_bounds__(256) void k_wt2(const float* __restrict__ W, u16* __restrict__ Wt,
                                             int K, int N, int rs, int ro) {
  __shared__ u16 t[64][80];
  int n0 = blockIdx.x * 64, k0 = blockIdx.y * 64;
#pragma unroll
  for (int p = 0; p < 4; ++p) {
    int id = threadIdx.x + p * 256;
    int row = id >> 4, c4 = (id & 15) * 4;
    float4 v = *(const float4*)(W + (size_t)(k0 + row) * N + n0 + c4);
    t[c4 + 0][row] = f2bf(v.x);
    t[c4 + 1][row] = f2bf(v.y);
    t[c4 + 2][row] = f2bf(v.z);
    t[c4 + 3][row] = f2bf(v.w);
  }
  __syncthreads();
#pragma unroll
  for (int p = 0; p < 2; ++p) {
    int id = threadIdx.x + p * 256;
    int row = id >> 3, c8 = (id & 7) * 8;
    *(us8*)(Wt + ((size_t)(n0 + row) * rs + ro) * K + k0 + c8) = *(const us8*)&t[row][c8];
  }
}

__global__ void k_cvt(const float* __restrict__ x, u16* __restrict__ y, int n4) {
  for (int i = blockIdx.x * 256 + threadIdx.x; i < n4; i += gridDim.x * 256) {
    float4 v = ((const float4*)x)[i];
    us4 p; p[0] = f2bf(v.x); p[1] = f2bf(v.y); p[2] = f2bf(v.z); p[3] = f2bf(v.w);
    ((us4*)y)[i] = p;
  }
}

// sum split-K planes (+ optional dst accumulate)
__global__ void k_reduce_add(const float* __restrict__ p, float* __restrict__ dst,
                             int n, int planes, int addDst) {
  for (int i = blockIdx.x * 256 + threadIdx.x; i < n; i += gridDim.x * 256) {
    float s = addDst ? dst[i] : 0.f;
    for (int z = 0; z < planes; ++z) s += p[(size_t)z * n + i];
    dst[i] = s;
  }
}

__global__ void k_rope_table(float* __restrict__ cosT, float* __restrict__ sinT) {
  int i = blockIdx.x * blockDim.x + threadIdx.x;
  if (i >= 18 * 64) return;
  int p = i >> 6, d = i & 63;
  float theta = powf(10000.f, -(float)(d & 31) / 32.f);
  float ang = (float)p * theta;
  cosT[i] = cosf(ang);
  sinT[i] = sinf(ang);
}

__global__ void k_fine_embed(const int* __restrict__ ids, const int* __restrict__ cspp,
                             const float* __restrict__ f_wte, const float* __restrict__ f_pos,
                             const float* __restrict__ f_adapt, float* __restrict__ xF) {
  int csp = fix_csp(cspp);
  for (int idx = blockIdx.x * 256 + threadIdx.x; idx < T_FINE * 1024; idx += gridDim.x * 256) {
    int r = idx >> 10, d = idx & 1023;
    int c = r / 18, j = r - c * 18;
    float v;
    if (j == 0)      v = f_adapt[csp * 1024 + d];
    else if (j == 1) v = f_pos[c * 1024 + d];
    else             v = f_wte[(size_t)ids[c * 16 + j - 2] * 1024 + d];
    xF[idx] = v;
  }
}

__global__ __launch_bounds__(256) void k_rmsnorm_bf(const float* __restrict__ x,
                                                    const float* __restrict__ w,
                                                    u16* __restrict__ y) {
  int t = blockIdx.x;
  const float4 v = *(const float4*)(x + (size_t)t * 1024 + threadIdx.x * 4);
  float ss = v.x * v.x + v.y * v.y + v.z * v.z + v.w * v.w;
#pragma unroll
  for (int off = 32; off; off >>= 1) ss += __shfl_xor(ss, off);
  __shared__ float ps[4];
  if ((threadIdx.x & 63) == 0) ps[threadIdx.x >> 6] = ss;
  __syncthreads();
  float inv = rsqrtf((ps[0] + ps[1] + ps[2] + ps[3]) * (1.f / 1024.f) + 1e-5f);
  const float4 wv = *(const float4*)(w + threadIdx.x * 4);
  us4 o;
  o[0] = f2bf(v.x * inv * wv.x); o[1] = f2bf(v.y * inv * wv.y);
  o[2] = f2bf(v.z * inv * wv.z); o[3] = f2bf(v.w * inv * wv.w);
  *(us4*)(y + (size_t)t * 1024 + threadIdx.x * 4) = o;
}

__global__ __launch_bounds__(256) void k_rmsnorm_pack_bf(const float* __restrict__ x,
                                                         const float* __restrict__ w,
                                                         u16* __restrict__ y) {
  int b = blockIdx.x;
  int c = b >> 4, r = b & 15;
  const float* xr = x + (size_t)(c * 18 + 2 + r) * 1024;
  const float4 v = *(const float4*)(xr + threadIdx.x * 4);
  float ss = v.x * v.x + v.y * v.y + v.z * v.z + v.w * v.w;
#pragma unroll
  for (int off = 32; off; off >>= 1) ss += __shfl_xor(ss, off);
  __shared__ float ps[4];
  if ((threadIdx.x & 63) == 0) ps[threadIdx.x >> 6] = ss;
  __syncthreads();
  float inv = rsqrtf((ps[0] + ps[1] + ps[2] + ps[3]) * (1.f / 1024.f) + 1e-5f);
  const float4 wv = *(const float4*)(w + threadIdx.x * 4);
  us4 o;
  o[0] = f2bf(v.x * inv * wv.x); o[1] = f2bf(v.y * inv * wv.y);
  o[2] = f2bf(v.z * inv * wv.z); o[3] = f2bf(v.w * inv * wv.w);
  *(us4*)(y + (size_t)b * 1024 + threadIdx.x * 4) = o;
}

__global__ __launch_bounds__(256) void k_rope(float* __restrict__ qkv,
                                              const float* __restrict__ cosT,
                                              const float* __restrict__ sinT) {
  int t = blockIdx.x;
  int p = t % 18;
  float* row = qkv + (size_t)t * 3072;
#pragma unroll
  for (int i = 0; i < 4; ++i) {
    int it = threadIdx.x + i * 256;
    int s = it >> 9, rem = it & 511, h = rem >> 5, d = rem & 31;
    float* px = row + s * 1024 + h * 64 + d;
    float x1 = px[0], x2 = px[32];
    float cv = cosT[p * 64 + d], sv = sinT[p * 64 + d];
    px[0]  = x1 * cv - x2 * sv;
    px[32] = x2 * cv + x1 * sv;
  }
}

// ---------------- fine attention: 4 waves/block, wave = head, LDS-staged ----------------
__global__ __launch_bounds__(256) void k_attn_fine2(const float* __restrict__ qkv,
                                                    u16* __restrict__ out) {
  __shared__ float q[4][18][68], k[4][18][68], v[4][18][68], s[4][18][20];
  int c = blockIdx.x;
  int w = threadIdx.x >> 6, lane = threadIdx.x & 63;
  int h = blockIdx.y * 4 + w;
  const float* base = qkv + (size_t)c * 18 * 3072 + h * 64;
#pragma unroll 3
  for (int r = 0; r < 18; ++r) {
    q[w][r][lane] = base[(size_t)r * 3072 + lane];
    k[w][r][lane] = base[(size_t)r * 3072 + 1024 + lane];
    v[w][r][lane] = base[(size_t)r * 3072 + 2048 + lane];
  }
  __syncthreads();
#pragma unroll
  for (int it = 0; it < 6; ++it) {
    int idx = lane + it * 64;
    if (idx < 324) {
      int qi = (idx * 3641) >> 16;
      int ki = idx - qi * 18;
      const float* qr = q[w][qi];
      const float* kr = k[w][ki];
      float a = 0.f;
#pragma unroll
      for (int d = 0; d < 64; d += 4) {
        float4 x = *(const float4*)&qr[d];
        float4 y = *(const float4*)&kr[d];
        a += x.x * y.x + x.y * y.y + x.z * y.z + x.w * y.w;
      }
      s[w][qi][ki] = a * 0.125f;
    }
  }
  __syncthreads();
  if (lane < 18) {
    float mx = -1e30f;
#pragma unroll
    for (int j = 0; j < 18; ++j) mx = fmaxf(mx, s[w][lane][j]);
    float sum = 0.f;
#pragma unroll
    for (int j = 0; j < 18; ++j) { float e = expf(s[w][lane][j] - mx); s[w][lane][j] = e; sum += e; }
    float inv = 1.f / sum;
#pragma unroll
    for (int j = 0; j < 18; ++j) s[w][lane][j] *= inv;
  }
  __syncthreads();
  float vcol[18];
#pragma unroll
  for (int ki = 0; ki < 18; ++ki) vcol[ki] = v[w][ki][lane];
#pragma unroll 2
  for (int qi = 0; qi < 18; ++qi) {
    float o = 0.f;
#pragma unroll
    for (int ki = 0; ki < 18; ++ki) o += s[w][qi][ki] * vcol[ki];
    out[(size_t)(c * 18 + qi) * 1024 + h * 64 + lane] = f2bf(o);
  }
}

// ======= decoder attention v3: block per (bq, head), shared K/V staged in LDS ==========
// Keys of token t (=18bq+r): block-starts {18m: m<=bq} ∪ own-block {18bq+1..t}.
// Staged rows: i<=bq -> kv=18i ; i>bq -> kv=18bq+(i-bq). Query r uses rows 0..bq+r.
__global__ __launch_bounds__(512) void k_attn_dec3(const float* __restrict__ qkv,
                                                   u16* __restrict__ out) {
  extern __shared__ float dyn[];
  float* Kl = dyn;                   // [146][65]
  float* Vl = Kl + 146 * 65;         // [146][65]
  float* Ql = Vl + 146 * 65;         // [18][65]
  float* Sw = Ql + 18 * 65;          // [8][148]
  const int bq = blockIdx.x, h = blockIdx.y;
  const int w = threadIdx.x >> 6, lane = threadIdx.x & 63;
  const int t0 = 18 * bq;
  const int nq = (bq < 128) ? 18 : 2;          // t=2304,2305 for bq=128
  const int nstage = (bq < 128) ? (bq + 18) : 130;

  {
    int rr = threadIdx.x >> 2, c = threadIdx.x & 3;     // 128 rows per sweep
    for (int row = rr; row < nstage; row += 128) {
      int kv = (row <= bq) ? 18 * row : t0 + (row - bq);
      const float* kp = qkv + (size_t)kv * 3072 + 1024 + h * 64 + c * 16;
#pragma unroll
      for (int q4 = 0; q4 < 4; ++q4) {
        float4 a = *(const float4*)(kp + q4 * 4);
        float4 b = *(const float4*)(kp + 1024 + q4 * 4);
        int d = c * 16 + q4 * 4;
        float* kd = Kl + row * 65 + d;
        float* vd = Vl + row * 65 + d;
        kd[0] = a.x; kd[1] = a.y; kd[2] = a.z; kd[3] = a.w;
        vd[0] = b.x; vd[1] = b.y; vd[2] = b.z; vd[3] = b.w;
      }
    }
    if (rr < nq) {
      const float* qp = qkv + (size_t)(t0 + rr) * 3072 + h * 64 + c * 16;
#pragma unroll
      for (int q4 = 0; q4 < 4; ++q4) {
        float4 a = *(const float4*)(qp + q4 * 4);
        int d = c * 16 + q4 * 4;
        float* qd = Ql + rr * 65 + d;
        qd[0] = a.x; qd[1] = a.y; qd[2] = a.z; qd[3] = a.w;
      }
    }
  }
  __syncthreads();

  for (int r = w; r < nq; r += 8) {
    const int nk = bq + 1 + r;                 // rows 0..bq+r (bq=128: 129+r)
    float* S = Sw + w * 148;
    const float* qr = Ql + r * 65;
    float mx = -1e30f;
    for (int i = lane; i < nk; i += 64) {
      const float* kr = Kl + i * 65;
      float a = 0.f;
#pragma unroll
      for (int d = 0; d < 64; ++d) a += qr[d] * kr[d];
      a *= 0.125f;
      S[i] = a;
      mx = fmaxf(mx, a);
    }
#pragma unroll
    for (int off = 32; off; off >>= 1) mx = fmaxf(mx, __shfl_xor(mx, off));
    float sum = 0.f;
    for (int i = lane; i < nk; i += 64) { float e = expf(S[i] - mx); S[i] = e; sum += e; }
#pragma unroll
    for (int off = 32; off; off >>= 1) sum += __shfl_xor(sum, off);
    float inv = 1.f / sum;
    __builtin_amdgcn_wave_barrier();           // keep compiler from reordering S reads
    float o = 0.f;
    for (int i = 0; i < nk; ++i) o += S[i] * Vl[i * 65 + lane];
    out[(size_t)(t0 + r) * 1024 + h * 64 + lane] = f2bf(o * inv);
  }
}

// ---------------- decoder attention v2 (fallback) ----------------
__global__ __launch_bounds__(256) void k_attn_dec2(const float* __restrict__ qkv,
                                                   u16* __restrict__ out) {
  __shared__ float sc_s[4][160];
  int t = blockIdx.x;
  int w = threadIdx.x >> 6, lane = threadIdx.x & 63;
  int h = blockIdx.y * 4 + w;
  float* sc = sc_s[w];
  int bq = t / 18;
  int nstart = bq + 1;
  int nown = t - 18 * bq;
  int nk = nstart + nown;
  int g = lane >> 2, j = lane & 3;
  const float* qb = qkv + (size_t)t * 3072 + h * 64 + j * 16;
  float4 q0 = *(const float4*)(qb);
  float4 q1 = *(const float4*)(qb + 4);
  float4 q2 = *(const float4*)(qb + 8);
  float4 q3 = *(const float4*)(qb + 12);
  for (int i0 = 0; i0 < nk; i0 += 16) {
    int i = i0 + g;
    float p = 0.f;
    if (i < nk) {
      int kv = (i < nstart) ? 18 * i : 18 * bq + (i - nstart) + 1;
      const float* kp = qkv + (size_t)kv * 3072 + 1024 + h * 64 + j * 16;
      float4 k0 = *(const float4*)(kp);
      float4 k1 = *(const float4*)(kp + 4);
      float4 k2 = *(const float4*)(kp + 8);
      float4 k3 = *(const float4*)(kp + 12);
      p = q0.x * k0.x + q0.y * k0.y + q0.z * k0.z + q0.w * k0.w
        + q1.x * k1.x + q1.y * k1.y + q1.z * k1.z + q1.w * k1.w
        + q2.x * k2.x + q2.y * k2.y + q2.z * k2.z + q2.w * k2.w
        + q3.x * k3.x + q3.y * k3.y + q3.z * k3.z + q3.w * k3.w;
    }
    p += __shfl_xor(p, 1);
    p += __shfl_xor(p, 2);
    if (i < nk && j == 0) sc[i] = p * 0.125f;
  }
  __syncthreads();
  float mx = -1e30f;
  for (int i = lane; i < nk; i += 64) mx = fmaxf(mx, sc[i]);
#pragma unroll
  for (int off = 32; off; off >>= 1) mx = fmaxf(mx, __shfl_xor(mx, off));
  float sum = 0.f;
  for (int i = lane; i < nk; i += 64) { float e = expf(sc[i] - mx); sc[i] = e; sum += e; }
#pragma unroll
  for (int off = 32; off; off >>= 1) sum += __shfl_xor(sum, off);
  float inv = 1.f / sum;
  __syncthreads();
  const float* vb = qkv + 2048 + h * 64 + lane;
  float o0 = 0.f, o1 = 0.f, o2 = 0.f, o3 = 0.f;
  int i = 0;
  for (; i + 4 <= nk; i += 4) {
    int ia = i, ib = i + 1, ic = i + 2, id = i + 3;
    int kva = (ia < nstart) ? 18 * ia : 18 * bq + (ia - nstart) + 1;
    int kvb = (ib < nstart) ? 18 * ib : 18 * bq + (ib - nstart) + 1;
    int kvc = (ic < nstart) ? 18 * ic : 18 * bq + (ic - nstart) + 1;
    int kvd = (id < nstart) ? 18 * id : 18 * bq + (id - nstart) + 1;
    o0 += sc[ia] * vb[(size_t)kva * 3072];
    o1 += sc[ib] * vb[(size_t)kvb * 3072];
    o2 += sc[ic] * vb[(size_t)kvc * 3072];
    o3 += sc[id] * vb[(size_t)kvd * 3072];
  }
  for (; i < nk; ++i) {
    int kv = (i < nstart) ? 18 * i : 18 * bq + (i - nstart) + 1;
    o0 += sc[i] * vb[(size_t)kv * 3072];
  }
  float o = (o0 + o1) + (o2 + o3);
  out[(size_t)t * 1024 + h * 64 + lane] = f2bf(o * inv);
}

// ---------------- decoder input assembly (zeroes pad rows 2306..MPAD-1) ----------------
__global__ void k_assemble(const int* __restrict__ ids, const int* __restrict__ cspp,
                           const float* __restrict__ fx, const float* __restrict__ dummy_fx,
                           const float* __restrict__ sep, const float* __restrict__ wte,
                           float* __restrict__ xD) {
  int csp = fix_csp(cspp);
  for (int idx = blockIdx.x * 256 + threadIdx.x; idx < MPAD * 1024; idx += gridDim.x * 256) {
    int t = idx >> 10, d = idx & 1023;
    float v;
    if (t >= L_DEC)     v = 0.f;
    else if (t == 2305) v = sep[d];
    else if (t == 2304) v = fx[127 * 1024 + d];
    else {
      int k = t / 18, r = t - k * 18;
      if (r == 0)      v = (k == 0) ? dummy_fx[csp * 1024 + d] : fx[(k - 1) * 1024 + d];
      else if (r == 1) v = sep[d];
      else             v = wte[(size_t)ids[k * 16 + r - 2] * 1024 + d];
    }
    xD[idx] = v;
  }
}

extern "C" void kernel_launch(void* const* d_in, const int* in_sizes, int n_in,
                              void* d_out, int out_size, void* d_ws, size_t ws_size,
                              hipStream_t stream) {
  const int*   input_ids = (const int*)d_in[0];
  const int*   cspp      = (const int*)d_in[1];
  const float* f_wte     = (const float*)d_in[2];
  const float* f_pos     = (const float*)d_in[3];
  const float* f_adapt   = (const float*)d_in[4];
  const float* f_ln1     = (const float*)d_in[5];
  const float* f_ln2     = (const float*)d_in[6];
  const float* f_wqkv    = (const float*)d_in[7];
  const float* f_wo      = (const float*)d_in[8];
  const float* f_wg      = (const float*)d_in[9];
  const float* f_wu      = (const float*)d_in[10];
  const float* f_wd      = (const float*)d_in[11];
  const float* f_norm    = (const float*)d_in[12];
  const float* f_proj    = (const float*)d_in[13];
  const float* dummy_fx  = (const float*)d_in[14];
  const float* wte       = (const float*)d_in[15];
  const float* sep       = (const float*)d_in[16];
  const float* d_ln1     = (const float*)d_in[17];
  const float* d_ln2     = (const float*)d_in[18];
  const float* d_wqkv    = (const float*)d_in[19];
  const float* d_wo      = (const float*)d_in[20];
  const float* d_wg      = (const float*)d_in[21];
  const float* d_wu      = (const float*)d_in[22];
  const float* d_wd      = (const float*)d_in[23];
  const float* d_norm    = (const float*)d_in[24];
  const float* w_out     = (const float*)d_in[25];

  // ---- d_ws: rope tables + bufH (bf16) + (if room) bf16 w_out ----
  float* cosT = (float*)d_ws;
  float* sinT = cosT + 1152;
  u16*   bufH = (u16*)(sinT + 1152);                 // [MPAD][1024] bf16
  u16*   w_outb = bufH + (size_t)MPAD * 1024;        // [32000][1024] bf16 (optional)
  const size_t WS_NEED = 2 * 1152 * 4 + (size_t)MPAD * 1024 * 2 + (size_t)32000 * 1024 * 2;
  const bool big_ws = ws_size >= WS_NEED;

  // ---- d_out scratch (head GEMM reads only ws buffers, so it may overwrite all) ----
  float* o       = (float*)d_out;
  float* xF      = o;                                   // [2304][1024] f32
  float* xD      = xF + (size_t)T_FINE * 1024;          // [MPAD][1024] f32
  float* fx      = xD + (size_t)MPAD * 1024;            // [128][1024] f32
  float* bufQKV  = fx + 128 * 1024;                     // [MPAD][3072] f32
  u16*   bufA    = (u16*)(bufQKV + (size_t)MPAD * 3072);// [MPAD][1024] bf16
  u16*   bufGb   = bufA + (size_t)MPAD * 1024;          // [MPAD][4096] bf16 (silu out)
  u16*   packedb = bufGb + (size_t)MPAD * 4096;         // [128][16384] bf16
  u16*   Wt      = packedb + (size_t)128 * 16384;       // [8192][1024] bf16 staging
  u16*   projb   = Wt + (size_t)8192 * 1024;            // [1024][16384] bf16
  float* spk     = (float*)(projb + (size_t)1024 * 16384); // split-K planes

  const size_t ATTN_LDS = (size_t)(146 * 65 * 2 + 18 * 65 + 8 * 148) * 4;  // 85,336 B
  hipError_t eattn = hipFuncSetAttribute(
      reinterpret_cast<const void*>(&k_attn_dec3),
      hipFuncAttributeMaxDynamicSharedMemorySize, (int)ATTN_LDS);

#define GEMM_BT(EPI, Ap, Bp, Cp, Cbp, Mpad, N, K, Mstore, S) \
  k_gemm_bt<EPI><<<dim3((N) / 128, (Mpad) / 128, (S)), 256, 0, stream>>>((Ap), (Bp), (Cp), (Cbp), (N), (K), (Mstore), (K) / (S))

  k_rope_table<<<5, 256, 0, stream>>>(cosT, sinT);
  k_fine_embed<<<2048, 256, 0, stream>>>(input_ids, cspp, f_wte, f_pos, f_adapt, xF);

  // ---- fine (compressor) layers ----
  for (int i = 0; i < 2; ++i) {
    k_rmsnorm_bf<<<T_FINE, 256, 0, stream>>>(xF, f_ln1 + i * 1024, bufH);
    k_wt2<<<dim3(48, 16), 256, 0, stream>>>(f_wqkv + (size_t)i * 1024 * 3072, Wt, 1024, 3072, 1, 0);
    GEMM_BT(0, bufH, Wt, bufQKV, (u16*)nullptr, T_FINE, 3072, 1024, T_FINE, 1);
    k_rope<<<T_FINE, 256, 0, stream>>>(bufQKV, cosT, sinT);
    k_attn_fine2<<<dim3(128, 4), 256, 0, stream>>>(bufQKV, bufA);
    k_wt2<<<dim3(16, 16), 256, 0, stream>>>(f_wo + (size_t)i * 1024 * 1024, Wt, 1024, 1024, 1, 0);
    GEMM_BT(1, bufA, Wt, xF, (u16*)nullptr, T_FINE, 1024, 1024, T_FINE, 1);
    k_rmsnorm_bf<<<T_FINE, 256, 0, stream>>>(xF, f_ln2 + i * 1024, bufH);
    k_wt2<<<dim3(64, 16), 256, 0, stream>>>(f_wg + (size_t)i * 1024 * 4096, Wt, 1024, 4096, 2, 0);
    k_wt2<<<dim3(64, 16), 256, 0, stream>>>(f_wu + (size_t)i * 1024 * 4096, Wt, 1024, 4096, 2, 1);
    GEMM_BT(2, bufH, Wt, (float*)nullptr, bufGb, T_FINE, 8192, 1024, T_FINE, 1);
    k_wt2<<<dim3(16, 64), 256, 0, stream>>>(f_wd + (size_t)i * 4096 * 1024, Wt, 4096, 1024, 1, 0);
    GEMM_BT(0, bufGb, Wt, spk, (u16*)nullptr, T_FINE, 1024, 4096, T_FINE, 4);
    k_reduce_add<<<2048, 256, 0, stream>>>(spk, xF, T_FINE * 1024, 4, 1);
  }

  // ---- fx = packed @ f_proj^T (split-K 32) ----
  k_rmsnorm_pack_bf<<<2048, 256, 0, stream>>>(xF, f_norm, packedb);
  k_cvt<<<2048, 256, 0, stream>>>(f_proj, projb, 1024 * 16384 / 4);
  GEMM_BT(0, packedb, projb, spk, (u16*)nullptr, 128, 1024, 16384, 128, 32);
  k_reduce_add<<<512, 256, 0, stream>>>(spk, fx, 128 * 1024, 32, 0);

  // ---- decoder ----
  k_assemble<<<2048, 256, 0, stream>>>(input_ids, cspp, fx, dummy_fx, sep, wte, xD);
  for (int i = 0; i < 2; ++i) {
    k_rmsnorm_bf<<<MPAD, 256, 0, stream>>>(xD, d_ln1 + i * 1024, bufH);
    k_wt2<<<dim3(48, 16), 256, 0, stream>>>(d_wqkv + (size_t)i * 1024 * 3072, Wt, 1024, 3072, 1, 0);
    GEMM_BT(0, bufH, Wt, bufQKV, (u16*)nullptr, MPAD, 3072, 1024, MPAD, 1);
    k_rope<<<L_DEC, 256, 0, stream>>>(bufQKV, cosT, sinT);
    if (eattn == hipSuccess) {
      k_attn_dec3<<<dim3(129, 16), 512, ATTN_LDS, stream>>>(bufQKV, bufA);
    } else {
      k_attn_dec2<<<dim3(L_DEC, 4), 256, 0, stream>>>(bufQKV, bufA);
    }
    k_wt2<<<dim3(16, 16), 256, 0, stream>>>(d_wo + (size_t)i * 1024 * 1024, Wt, 1024, 1024, 1, 0);
    GEMM_BT(1, bufA, Wt, xD, (u16*)nullptr, MPAD, 1024, 1024, MPAD, 1);
    k_rmsnorm_bf<<<MPAD, 256, 0, stream>>>(xD, d_ln2 + i * 1024, bufH);
    k_wt2<<<dim3(64, 16), 256, 0, stream>>>(d_wg + (size_t)i * 1024 * 4096, Wt, 1024, 4096, 2, 0);
    k_wt2<<<dim3(64, 16), 256, 0, stream>>>(d_wu + (size_t)i * 1024 * 4096, Wt, 1024, 4096, 2, 1);
    GEMM_BT(2, bufH, Wt, (float*)nullptr, bufGb, MPAD, 8192, 1024, MPAD, 1);
    k_wt2<<<dim3(16, 64), 256, 0, stream>>>(d_wd + (size_t)i * 4096 * 1024, Wt, 4096, 1024, 1, 0);
    GEMM_BT(0, bufGb, Wt, spk, (u16*)nullptr, MPAD, 1024, 4096, MPAD, 4);
    k_reduce_add<<<2048, 256, 0, stream>>>(spk, xD, MPAD * 1024, 4, 1);
  }

  // ---- head: out = rmsnorm(xD) @ w_out^T ----
  k_rmsnorm_bf<<<MPAD, 256, 0, stream>>>(xD, d_norm, bufH);
  if (big_ws) {
    k_cvt<<<2048, 256, 0, stream>>>(w_out, w_outb, 32000 * 1024 / 4);
    hipError_t ae = hipFuncSetAttribute(
        reinterpret_cast<const void*>(&k_gemm3<0>),
        hipFuncAttributeMaxDynamicSharedMemorySize, 131072);
    if (ae == hipSuccess) {
      k_gemm3<0><<<dim3(125, 10), 512, 131072, stream>>>(bufH, w_outb, o, 32000, 1024, L_DEC);
    } else {
      k_gemm2<0><<<dim3(125, 10), 512, 0, stream>>>(bufH, w_outb, o, nullptr, 32000, 1024, L_DEC);
    }
  } else {
    k_gemm_hf<<<dim3(250, MPAD / 128), 256, 0, stream>>>(bufH, w_out, o, 32000, 1024, L_DEC);
  }
#undef GEMM_BT
}

// Round 7
// 1387.392 us; speedup vs baseline: 1.0838x; 1.0838x over previous
//
#include <hip/hip_runtime.h>
#include <math.h>

#define L_DEC 2306
#define MPAD 2560      // 10*256, decoder rows padded
#define T_FINE 2304    // 9*256, exact

typedef float f32x4 __attribute__((ext_vector_type(4)));
typedef __bf16 bf16x8 __attribute__((ext_vector_type(8)));
typedef unsigned short u16;
typedef unsigned short us4 __attribute__((ext_vector_type(4)));
typedef unsigned short us8 __attribute__((ext_vector_type(8)));

#define GLOAD16(g, l) __builtin_amdgcn_global_load_lds( \
    (const __attribute__((address_space(1))) unsigned int*)(g), \
    (__attribute__((address_space(3))) unsigned int*)(l), 16, 0, 0)

__device__ __forceinline__ u16 f2bf(float f) {
  unsigned u = __float_as_uint(f);
  u += 0x7fffu + ((u >> 16) & 1u);   // RNE
  return (u16)(u >> 16);
}

__device__ __forceinline__ int fix_csp(const int* p) {
  int c = p[0];
  if ((unsigned)c <= 4u) return c;
  float f = __uint_as_float((unsigned)c);
  int c2 = (int)f;
  return ((unsigned)c2 <= 4u) ? c2 : 4;
}

// XCD-aware bijective block swizzle (m204). ROWMAJ=1: consecutive wg walk N (row bands).
// ROWMAJ=0: consecutive wg walk M (column bands) — better when B >> A (head GEMM).
template<int ROWMAJ>
__device__ __forceinline__ void xcd_map(int gx, int gy, int& bm, int& bn, int TS) {
  const int nwg = gx * gy;
  const int orig = blockIdx.y * gx + blockIdx.x;
  const int q8 = nwg >> 3, r8 = nwg & 7;
  const int xcd = orig & 7, idx8 = orig >> 3;
  const int wg = (xcd < r8 ? xcd * (q8 + 1) : r8 * (q8 + 1) + (xcd - r8) * q8) + idx8;
  if (ROWMAJ) { bm = (wg / gx) * TS; bn = (wg % gx) * TS; }
  else        { bm = (wg % gy) * TS; bn = (wg / gy) * TS; }
}

// ================= 256^2, BK=64, double-buffered, dynamic 128KB LDS (head) ==============
template<int EPI>
__global__ __launch_bounds__(512, 1) void k_gemm3(const u16* __restrict__ A,
                                                  const u16* __restrict__ B,
                                                  float* __restrict__ C,
                                                  int N, int K, int Mstore)
{
  extern __shared__ u16 lds[];   // [2 buf][A:16384 | B:16384] u16  (= 128 KB)
  const int tid = threadIdx.x;
  int bm, bn; xcd_map<0>(gridDim.x, gridDim.y, bm, bn, 256);
  const int w = tid >> 6, lane = tid & 63;
  const int wm = (w >> 2) * 128, wn = (w & 3) * 64;
  const int lr = lane & 15, kh = lane >> 4;

#define STAGE3(buf, kt) do {                                                   \
    u16* lA = lds + (buf) * 32768;                                             \
    u16* lB = lA + 16384;                                                      \
    _Pragma("unroll")                                                          \
    for (int p = 0; p < 4; ++p) {                                              \
      int e = p * 512 + tid;                                                   \
      int row = e >> 3;                                                        \
      int kc = ((e & 7) ^ (row & 7)) * 8;   /* pre-swizzled global k-offset */ \
      GLOAD16(A + (size_t)(bm + row) * K + (size_t)(kt) * 64 + kc, lA + e * 8);\
      GLOAD16(B + (size_t)(bn + row) * K + (size_t)(kt) * 64 + kc, lB + e * 8);\
    }                                                                          \
  } while (0)

  f32x4 acc[8][4] = {};
  const int nt = K >> 6;
  STAGE3(0, 0);
  __syncthreads();
  int cur = 0;
  for (int t = 0; t < nt; ++t) {
    if (t + 1 < nt) STAGE3(cur ^ 1, t + 1);
    const u16* pA = lds + cur * 32768;
    const u16* pB = pA + 16384;
    const int xr = (lr & 7) << 3;           // row-XOR for swizzled ds_read
#pragma unroll
    for (int kt2 = 0; kt2 < 2; ++kt2) {
      bf16x8 af[8], bf[4];
#pragma unroll
      for (int m = 0; m < 8; ++m)
        af[m] = *(const bf16x8*)&pA[(wm + m * 16 + lr) * 64 + ((kt2 * 32 + kh * 8) ^ xr)];
#pragma unroll
      for (int n = 0; n < 4; ++n)
        bf[n] = *(const bf16x8*)&pB[(wn + n * 16 + lr) * 64 + ((kt2 * 32 + kh * 8) ^ xr)];
#pragma unroll
      for (int m = 0; m < 8; ++m)
#pragma unroll
        for (int n = 0; n < 4; ++n)
          acc[m][n] = __builtin_amdgcn_mfma_f32_16x16x32_bf16(af[m], bf[n], acc[m][n], 0, 0, 0);
    }
    __syncthreads();
    cur ^= 1;
  }
#undef STAGE3

#pragma unroll
  for (int m = 0; m < 8; ++m) {
    int gr0 = bm + wm + m * 16 + kh * 4;
#pragma unroll
    for (int n = 0; n < 4; ++n) {
      int gc = bn + wn + n * 16 + lr;
#pragma unroll
      for (int r = 0; r < 4; ++r) {
        int gr = gr0 + r;
        if (gr < Mstore) C[(size_t)gr * N + gc] = acc[m][n][r];
      }
    }
  }
}

// ================= 256^2 2-phase BK=32 (static 64KB LDS) — head fallback ================
template<int EPI>
__global__ __launch_bounds__(512, 1) void k_gemm2(const u16* __restrict__ A,
                                                  const u16* __restrict__ B,
                                                  float* __restrict__ C,
                                                  u16* __restrict__ Cb,
                                                  int N, int K, int Mstore)
{
  __shared__ u16 As[2][8192];
  __shared__ u16 Bs[2][8192];
  const int tid = threadIdx.x;
  int bm, bn; xcd_map<1>(gridDim.x, gridDim.y, bm, bn, 256);
  const int w = tid >> 6, lane = tid & 63;
  const int wm = (w >> 2) * 128, wn = (w & 3) * 64;
  const int lr = lane & 15, kh = lane >> 4;
  const int r0 = tid >> 2;
  const int ksrc = 8 * ((tid & 3) ^ ((tid >> 3) & 3));
  const u16* ga = A + (size_t)(bm + r0) * K + ksrc;
  const u16* gb = B + (size_t)(bn + r0) * K + ksrc;
  const size_t rstep = (size_t)128 * K;
  const int cola = (kh * 8) ^ (((lr >> 1) & 3) << 3);

#define STAGE2(buf, kt) do {                                   \
    const u16* gA = ga + (size_t)(kt) * 32;                    \
    const u16* gB = gb + (size_t)(kt) * 32;                    \
    GLOAD16(gA,         &As[buf][tid * 8]);                    \
    GLOAD16(gA + rstep, &As[buf][tid * 8 + 4096]);             \
    GLOAD16(gB,         &Bs[buf][tid * 8]);                    \
    GLOAD16(gB + rstep, &Bs[buf][tid * 8 + 4096]);             \
  } while (0)

  f32x4 acc[8][4] = {};
  const int nt = K >> 5;
  STAGE2(0, 0);
  __syncthreads();
  int cur = 0;
  for (int t = 0; t < nt; ++t) {
    if (t + 1 < nt) STAGE2(cur ^ 1, t + 1);
    bf16x8 af[8], bf[4];
#pragma unroll
    for (int m = 0; m < 8; ++m)
      af[m] = *(const bf16x8*)&As[cur][(wm + m * 16 + lr) * 32 + cola];
#pragma unroll
    for (int n = 0; n < 4; ++n)
      bf[n] = *(const bf16x8*)&Bs[cur][(wn + n * 16 + lr) * 32 + cola];
#pragma unroll
    for (int m = 0; m < 8; ++m)
#pragma unroll
      for (int n = 0; n < 4; ++n)
        acc[m][n] = __builtin_amdgcn_mfma_f32_16x16x32_bf16(af[m], bf[n], acc[m][n], 0, 0, 0);
    __syncthreads();
    cur ^= 1;
  }
#undef STAGE2

#pragma unroll
  for (int m = 0; m < 8; ++m) {
    int gr0 = bm + wm + m * 16 + kh * 4;
#pragma unroll
    for (int n = 0; n < 4; ++n) {
      int gc = bn + wn + n * 16 + lr;
#pragma unroll
      for (int r = 0; r < 4; ++r) {
        int gr = gr0 + r;
        if (gr < Mstore) C[(size_t)gr * N + gc] = acc[m][n][r];
      }
    }
  }
}

// ================= 128^2 MFMA GEMM (m97 + T2 swizzle + XCD swizzle) =====================
// EPI=0: store split-K plane z. EPI=1: C += acc. EPI=2: silu-fused g|u -> Cb bf16.
// EPI=3: qkv with fused rope (pos = gr%18, q/k sections only) -> C f32.
template<int EPI>
__global__ __launch_bounds__(256) void k_gemm_bt(const u16* __restrict__ A,
                                                 const u16* __restrict__ B,
                                                 float* __restrict__ C,
                                                 u16* __restrict__ Cb,
                                                 const float* __restrict__ cosT,
                                                 const float* __restrict__ sinT,
                                                 int N, int K, int Mstore, int kchunk)
{
  __shared__ u16 As[4096];
  __shared__ u16 Bs[4096];
  const int tid = threadIdx.x;
  int bm, bn; xcd_map<1>(gridDim.x, gridDim.y, bm, bn, 128);
  const int k0 = blockIdx.z * kchunk;
  const int w = tid >> 6, lane = tid & 63;
  const int wm = (w >> 1) * 64, wn = (w & 1) * 64;
  const int lr = lane & 15, kh = lane >> 4;
  const int r0 = tid >> 2;
  const int ksrc = 8 * ((tid & 3) ^ ((tid >> 3) & 3));
  const int cola = (kh * 8) ^ (((lr >> 1) & 3) << 3);

  const u16* ga = A + (size_t)(bm + r0) * K + k0 + ksrc;
  const u16* gb = B + (size_t)(bn + r0) * K + k0 + ksrc;
  u16* la = &As[tid * 8];
  u16* lb = &Bs[tid * 8];
  const size_t rstep = (size_t)64 * K;

  f32x4 acc[4][4] = {};
  for (int kk = 0; kk < kchunk; kk += 32) {
    GLOAD16(ga, la); GLOAD16(ga + rstep, la + 2048);
    GLOAD16(gb, lb); GLOAD16(gb + rstep, lb + 2048);
    ga += 32; gb += 32;
    __syncthreads();
    bf16x8 af[4], bfr[4];
#pragma unroll
    for (int m = 0; m < 4; ++m)
      af[m] = *(const bf16x8*)&As[(wm + m * 16 + lr) * 32 + cola];
#pragma unroll
    for (int n = 0; n < 4; ++n)
      bfr[n] = *(const bf16x8*)&Bs[(wn + n * 16 + lr) * 32 + cola];
#pragma unroll
    for (int m = 0; m < 4; ++m)
#pragma unroll
      for (int n = 0; n < 4; ++n)
        acc[m][n] = __builtin_amdgcn_mfma_f32_16x16x32_bf16(af[m], bfr[n], acc[m][n], 0, 0, 0);
    __syncthreads();
  }

  float* Cz = (EPI == 0) ? C + (size_t)blockIdx.z * Mstore * N : C;
  const int N2 = N >> 1;
  const bool doRope = (EPI == 3) && ((bn + wn) < 2048);   // q/k sections, wave-uniform
#pragma unroll
  for (int m = 0; m < 4; ++m) {
    int gr0 = bm + wm + m * 16 + kh * 4;
#pragma unroll
    for (int r = 0; r < 4; ++r) {
      int gr = gr0 + r;
      if (EPI == 3) {
        int p = gr % 18;
        if (doRope) {
#pragma unroll
          for (int n2 = 0; n2 < 2; ++n2) {
            int d = n2 * 16 + lr;                      // 0..31
            float c = cosT[p * 64 + d], s = sinT[p * 64 + d];
            float x1 = acc[m][n2][r], x2 = acc[m][n2 + 2][r];
            if (gr < Mstore) {
              int gc = bn + wn + n2 * 16 + lr;
              C[(size_t)gr * N + gc]      = x1 * c - x2 * s;
              C[(size_t)gr * N + gc + 32] = x2 * c + x1 * s;
            }
          }
        } else if (gr < Mstore) {
#pragma unroll
          for (int n = 0; n < 4; ++n)
            C[(size_t)gr * N + bn + wn + n * 16 + lr] = acc[m][n][r];
        }
      } else if (EPI == 2) {
#pragma unroll
        for (int n = 0; n < 4; ++n) {
          float x = acc[m][n][r];
          float px = __shfl_xor(x, 1);          // partner u (all lanes execute)
          if (!(lr & 1) && gr < Mstore) {
            int gc = bn + wn + n * 16 + lr;
            float sgl = x / (1.f + expf(-x)) * px;
            Cb[(size_t)gr * N2 + (gc >> 1)] = f2bf(sgl);
          }
        }
      } else {
        if (gr < Mstore) {
#pragma unroll
          for (int n = 0; n < 4; ++n) {
            size_t off = (size_t)gr * N + bn + wn + n * 16 + lr;
            if (EPI == 0) Cz[off] = acc[m][n][r];
            else          C[off] += acc[m][n][r];
          }
        }
      }
    }
  }
}

// Head fallback when ws can't hold bf16 w_out.
__global__ __launch_bounds__(256) void k_gemm_hf(const u16* __restrict__ A,
                                                 const float* __restrict__ B,
                                                 float* __restrict__ C,
                                                 int N, int K, int Mstore)
{
  __shared__ u16 As[4096];
  __shared__ u16 Bs[4096];
  const int tid = threadIdx.x;
  const int bm = blockIdx.y * 128, bn = blockIdx.x * 128;
  const int w = tid >> 6, lane = tid & 63;
  const int wm = (w >> 1) * 64, wn = (w & 1) * 64;
  const int lr = lane & 15, kh = lane >> 4;
  const int r0 = tid >> 2;
  const int ksrc = 8 * ((tid & 3) ^ ((tid >> 3) & 3));
  const int cola = (kh * 8) ^ (((lr >> 1) & 3) << 3);
  const u16* ga = A + (size_t)(bm + r0) * K + ksrc;
  u16* la = &As[tid * 8];
  const size_t rstep = (size_t)64 * K;

  f32x4 acc[4][4] = {};
  for (int kk = 0; kk < K; kk += 32) {
    GLOAD16(ga, la); GLOAD16(ga + rstep, la + 2048);
    ga += 32;
#pragma unroll
    for (int p = 0; p < 4; ++p) {
      int e = tid + p * 256;
      int row = e >> 3, kc = (e & 7) * 4;
      int kcs = kc ^ (((row >> 1) & 3) << 3);
      float4 v = *(const float4*)(B + (size_t)(bn + row) * K + kk + kc);
      us4 pk; pk[0] = f2bf(v.x); pk[1] = f2bf(v.y); pk[2] = f2bf(v.z); pk[3] = f2bf(v.w);
      *(us4*)&Bs[row * 32 + kcs] = pk;
    }
    __syncthreads();
    bf16x8 af[4], bfr[4];
#pragma unroll
    for (int m = 0; m < 4; ++m)
      af[m] = *(const bf16x8*)&As[(wm + m * 16 + lr) * 32 + cola];
#pragma unroll
    for (int n = 0; n < 4; ++n)
      bfr[n] = *(const bf16x8*)&Bs[(wn + n * 16 + lr) * 32 + cola];
#pragma unroll
    for (int m = 0; m < 4; ++m)
#pragma unroll
      for (int n = 0; n < 4; ++n)
        acc[m][n] = __builtin_amdgcn_mfma_f32_16x16x32_bf16(af[m], bfr[n], acc[m][n], 0, 0, 0);
    __syncthreads();
  }
#pragma unroll
  for (int m = 0; m < 4; ++m) {
    int gr0 = bm + wm + m * 16 + kh * 4;
#pragma unroll
    for (int n = 0; n < 4; ++n) {
      int gc = bn + wn + n * 16 + lr;
#pragma unroll
      for (int r = 0; r < 4; ++r) {
        int gr = gr0 + r;
        if (gr < Mstore) C[(size_t)gr * N + gc] = acc[m][n][r];
      }
    }
  }
}

// ---- weight transpose-convert: W[K,N] f32 -> Wt[(n*rs+ro+z)][K] bf16; z selects W/W2 ----
__global__ __launch_bounds__(256) void k_wt2(const float* __restrict__ W,
                                             const float* __restrict__ W2,
                                             u16* __restrict__ Wt,
                                             int K, int N, int rs, int ro) {
  __shared__ u16 t[64][80];
  const float* src = (blockIdx.z == 0) ? W : W2;
  int roz = ro + blockIdx.z;
  int n0 = blockIdx.x * 64, k0 = blockIdx.y * 64;
#pragma unroll
  for (int p = 0; p < 4; ++p) {
    int id = threadIdx.x + p * 256;
    int row = id >> 4, c4 = (id & 15) * 4;
    float4 v = *(const float4*)(src + (size_t)(k0 + row) * N + n0 + c4);
    t[c4 + 0][row] = f2bf(v.x);
    t[c4 + 1][row] = f2bf(v.y);
    t[c4 + 2][row] = f2bf(v.z);
    t[c4 + 3][row] = f2bf(v.w);
  }
  __syncthreads();
#pragma unroll
  for (int p = 0; p < 2; ++p) {
    int id = threadIdx.x + p * 256;
    int row = id >> 3, c8 = (id & 7) * 8;
    *(us8*)(Wt + ((size_t)(n0 + row) * rs + roz) * K + k0 + c8) = *(const us8*)&t[row][c8];
  }
}

__global__ void k_cvt(const float* __restrict__ x, u16* __restrict__ y, int n4) {
  for (int i = blockIdx.x * 256 + threadIdx.x; i < n4; i += gridDim.x * 256) {
    float4 v = ((const float4*)x)[i];
    us4 p; p[0] = f2bf(v.x); p[1] = f2bf(v.y); p[2] = f2bf(v.z); p[3] = f2bf(v.w);
    ((us4*)y)[i] = p;
  }
}

// sum split-K planes (+ optional dst accumulate) — proj path only
__global__ void k_reduce_add(const float* __restrict__ p, float* __restrict__ dst,
                             int n, int planes, int addDst) {
  for (int i = blockIdx.x * 256 + threadIdx.x; i < n; i += gridDim.x * 256) {
    float s = addDst ? dst[i] : 0.f;
    for (int z = 0; z < planes; ++z) s += p[(size_t)z * n + i];
    dst[i] = s;
  }
}

// ---- fused: x += sum(planes); bufH = rmsnorm(x, w) bf16 (if NORM). grid = rows --------
template<int S, int NORM>
__global__ __launch_bounds__(256) void k_red_norm(const float* __restrict__ planes,
                                                  float* __restrict__ x,
                                                  const float* __restrict__ w,
                                                  u16* __restrict__ y) {
  const int t = blockIdx.x;
  const int n = gridDim.x * 1024;              // plane stride
  const size_t base = (size_t)t * 1024 + threadIdx.x * 4;
  float4 a = *(const float4*)(x + base);
#pragma unroll
  for (int s = 0; s < S; ++s) {
    float4 p = *(const float4*)(planes + (size_t)s * n + base);
    a.x += p.x; a.y += p.y; a.z += p.z; a.w += p.w;
  }
  *(float4*)(x + base) = a;
  if (NORM) {
    float ss = a.x * a.x + a.y * a.y + a.z * a.z + a.w * a.w;
#pragma unroll
    for (int off = 32; off; off >>= 1) ss += __shfl_xor(ss, off);
    __shared__ float ps[4];
    if ((threadIdx.x & 63) == 0) ps[threadIdx.x >> 6] = ss;
    __syncthreads();
    float inv = rsqrtf((ps[0] + ps[1] + ps[2] + ps[3]) * (1.f / 1024.f) + 1e-5f);
    const float4 wv = *(const float4*)(w + threadIdx.x * 4);
    us4 o;
    o[0] = f2bf(a.x * inv * wv.x); o[1] = f2bf(a.y * inv * wv.y);
    o[2] = f2bf(a.z * inv * wv.z); o[3] = f2bf(a.w * inv * wv.w);
    *(us4*)(y + base) = o;
  }
}

__global__ void k_rope_table(float* __restrict__ cosT, float* __restrict__ sinT) {
  int i = blockIdx.x * blockDim.x + threadIdx.x;
  if (i >= 18 * 64) return;
  int p = i >> 6, d = i & 63;
  float theta = powf(10000.f, -(float)(d & 31) / 32.f);
  float ang = (float)p * theta;
  cosT[i] = cosf(ang);
  sinT[i] = sinf(ang);
}

__global__ void k_fine_embed(const int* __restrict__ ids, const int* __restrict__ cspp,
                             const float* __restrict__ f_wte, const float* __restrict__ f_pos,
                             const float* __restrict__ f_adapt, float* __restrict__ xF) {
  int csp = fix_csp(cspp);
  for (int idx = blockIdx.x * 256 + threadIdx.x; idx < T_FINE * 1024; idx += gridDim.x * 256) {
    int r = idx >> 10, d = idx & 1023;
    int c = r / 18, j = r - c * 18;
    float v;
    if (j == 0)      v = f_adapt[csp * 1024 + d];
    else if (j == 1) v = f_pos[c * 1024 + d];
    else             v = f_wte[(size_t)ids[c * 16 + j - 2] * 1024 + d];
    xF[idx] = v;
  }
}

__global__ __launch_bounds__(256) void k_rmsnorm_bf(const float* __restrict__ x,
                                                    const float* __restrict__ w,
                                                    u16* __restrict__ y) {
  int t = blockIdx.x;
  const float4 v = *(const float4*)(x + (size_t)t * 1024 + threadIdx.x * 4);
  float ss = v.x * v.x + v.y * v.y + v.z * v.z + v.w * v.w;
#pragma unroll
  for (int off = 32; off; off >>= 1) ss += __shfl_xor(ss, off);
  __shared__ float ps[4];
  if ((threadIdx.x & 63) == 0) ps[threadIdx.x >> 6] = ss;
  __syncthreads();
  float inv = rsqrtf((ps[0] + ps[1] + ps[2] + ps[3]) * (1.f / 1024.f) + 1e-5f);
  const float4 wv = *(const float4*)(w + threadIdx.x * 4);
  us4 o;
  o[0] = f2bf(v.x * inv * wv.x); o[1] = f2bf(v.y * inv * wv.y);
  o[2] = f2bf(v.z * inv * wv.z); o[3] = f2bf(v.w * inv * wv.w);
  *(us4*)(y + (size_t)t * 1024 + threadIdx.x * 4) = o;
}

__global__ __launch_bounds__(256) void k_rmsnorm_pack_bf(const float* __restrict__ x,
                                                         const float* __restrict__ w,
                                                         u16* __restrict__ y) {
  int b = blockIdx.x;
  int c = b >> 4, r = b & 15;
  const float* xr = x + (size_t)(c * 18 + 2 + r) * 1024;
  const float4 v = *(const float4*)(xr + threadIdx.x * 4);
  float ss = v.x * v.x + v.y * v.y + v.z * v.z + v.w * v.w;
#pragma unroll
  for (int off = 32; off; off >>= 1) ss += __shfl_xor(ss, off);
  __shared__ float ps[4];
  if ((threadIdx.x & 63) == 0) ps[threadIdx.x >> 6] = ss;
  __syncthreads();
  float inv = rsqrtf((ps[0] + ps[1] + ps[2] + ps[3]) * (1.f / 1024.f) + 1e-5f);
  const float4 wv = *(const float4*)(w + threadIdx.x * 4);
  us4 o;
  o[0] = f2bf(v.x * inv * wv.x); o[1] = f2bf(v.y * inv * wv.y);
  o[2] = f2bf(v.z * inv * wv.z); o[3] = f2bf(v.w * inv * wv.w);
  *(us4*)(y + (size_t)b * 1024 + threadIdx.x * 4) = o;
}

// ---------------- fine attention: 4 waves/block, wave = head, LDS-staged ----------------
__global__ __launch_bounds__(256) void k_attn_fine2(const float* __restrict__ qkv,
                                                    u16* __restrict__ out) {
  __shared__ float q[4][18][68], k[4][18][68], v[4][18][68], s[4][18][20];
  int c = blockIdx.x;
  int w = threadIdx.x >> 6, lane = threadIdx.x & 63;
  int h = blockIdx.y * 4 + w;
  const float* base = qkv + (size_t)c * 18 * 3072 + h * 64;
#pragma unroll 3
  for (int r = 0; r < 18; ++r) {
    q[w][r][lane] = base[(size_t)r * 3072 + lane];
    k[w][r][lane] = base[(size_t)r * 3072 + 1024 + lane];
    v[w][r][lane] = base[(size_t)r * 3072 + 2048 + lane];
  }
  __syncthreads();
#pragma unroll
  for (int it = 0; it < 6; ++it) {
    int idx = lane + it * 64;
    if (idx < 324) {
      int qi = (idx * 3641) >> 16;
      int ki = idx - qi * 18;
      const float* qr = q[w][qi];
      const float* kr = k[w][ki];
      float a = 0.f;
#pragma unroll
      for (int d = 0; d < 64; d += 4) {
        float4 x = *(const float4*)&qr[d];
        float4 y = *(const float4*)&kr[d];
        a += x.x * y.x + x.y * y.y + x.z * y.z + x.w * y.w;
      }
      s[w][qi][ki] = a * 0.125f;
    }
  }
  __syncthreads();
  if (lane < 18) {
    float mx = -1e30f;
#pragma unroll
    for (int j = 0; j < 18; ++j) mx = fmaxf(mx, s[w][lane][j]);
    float sum = 0.f;
#pragma unroll
    for (int j = 0; j < 18; ++j) { float e = expf(s[w][lane][j] - mx); s[w][lane][j] = e; sum += e; }
    float inv = 1.f / sum;
#pragma unroll
    for (int j = 0; j < 18; ++j) s[w][lane][j] *= inv;
  }
  __syncthreads();
  float vcol[18];
#pragma unroll
  for (int ki = 0; ki < 18; ++ki) vcol[ki] = v[w][ki][lane];
#pragma unroll 2
  for (int qi = 0; qi < 18; ++qi) {
    float o = 0.f;
#pragma unroll
    for (int ki = 0; ki < 18; ++ki) o += s[w][qi][ki] * vcol[ki];
    out[(size_t)(c * 18 + qi) * 1024 + h * 64 + lane] = f2bf(o);
  }
}

// ======= decoder attention v3: block per (bq, head), shared K/V staged in LDS ==========
__global__ __launch_bounds__(512) void k_attn_dec3(const float* __restrict__ qkv,
                                                   u16* __restrict__ out) {
  extern __shared__ float dyn[];
  float* Kl = dyn;                   // [146][65]
  float* Vl = Kl + 146 * 65;         // [146][65]
  float* Ql = Vl + 146 * 65;         // [18][65]
  float* Sw = Ql + 18 * 65;          // [8][148]
  const int bq = blockIdx.x, h = blockIdx.y;
  const int w = threadIdx.x >> 6, lane = threadIdx.x & 63;
  const int t0 = 18 * bq;
  const int nq = (bq < 128) ? 18 : 2;
  const int nstage = (bq < 128) ? (bq + 18) : 130;

  {
    int rr = threadIdx.x >> 2, c = threadIdx.x & 3;
    for (int row = rr; row < nstage; row += 128) {
      int kv = (row <= bq) ? 18 * row : t0 + (row - bq);
      const float* kp = qkv + (size_t)kv * 3072 + 1024 + h * 64 + c * 16;
#pragma unroll
      for (int q4 = 0; q4 < 4; ++q4) {
        float4 a = *(const float4*)(kp + q4 * 4);
        float4 b = *(const float4*)(kp + 1024 + q4 * 4);
        int d = c * 16 + q4 * 4;
        float* kd = Kl + row * 65 + d;
        float* vd = Vl + row * 65 + d;
        kd[0] = a.x; kd[1] = a.y; kd[2] = a.z; kd[3] = a.w;
        vd[0] = b.x; vd[1] = b.y; vd[2] = b.z; vd[3] = b.w;
      }
    }
    if (rr < nq) {
      const float* qp = qkv + (size_t)(t0 + rr) * 3072 + h * 64 + c * 16;
#pragma unroll
      for (int q4 = 0; q4 < 4; ++q4) {
        float4 a = *(const float4*)(qp + q4 * 4);
        int d = c * 16 + q4 * 4;
        float* qd = Ql + rr * 65 + d;
        qd[0] = a.x; qd[1] = a.y; qd[2] = a.z; qd[3] = a.w;
      }
    }
  }
  __syncthreads();

  for (int r = w; r < nq; r += 8) {
    const int nk = bq + 1 + r;
    float* S = Sw + w * 148;
    const float* qr = Ql + r * 65;
    float mx = -1e30f;
    for (int i = lane; i < nk; i += 64) {
      const float* kr = Kl + i * 65;
      float a = 0.f;
#pragma unroll
      for (int d = 0; d < 64; ++d) a += qr[d] * kr[d];
      a *= 0.125f;
      S[i] = a;
      mx = fmaxf(mx, a);
    }
#pragma unroll
    for (int off = 32; off; off >>= 1) mx = fmaxf(mx, __shfl_xor(mx, off));
    float sum = 0.f;
    for (int i = lane; i < nk; i += 64) { float e = expf(S[i] - mx); S[i] = e; sum += e; }
#pragma unroll
    for (int off = 32; off; off >>= 1) sum += __shfl_xor(sum, off);
    float inv = 1.f / sum;
    __builtin_amdgcn_wave_barrier();
    float o = 0.f;
    for (int i = 0; i < nk; ++i) o += S[i] * Vl[i * 65 + lane];
    out[(size_t)(t0 + r) * 1024 + h * 64 + lane] = f2bf(o * inv);
  }
}

// ---------------- decoder attention v2 (fallback) ----------------
__global__ __launch_bounds__(256) void k_attn_dec2(const float* __restrict__ qkv,
                                                   u16* __restrict__ out) {
  __shared__ float sc_s[4][160];
  int t = blockIdx.x;
  int w = threadIdx.x >> 6, lane = threadIdx.x & 63;
  int h = blockIdx.y * 4 + w;
  float* sc = sc_s[w];
  int bq = t / 18;
  int nstart = bq + 1;
  int nown = t - 18 * bq;
  int nk = nstart + nown;
  int g = lane >> 2, j = lane & 3;
  const float* qb = qkv + (size_t)t * 3072 + h * 64 + j * 16;
  float4 q0 = *(const float4*)(qb);
  float4 q1 = *(const float4*)(qb + 4);
  float4 q2 = *(const float4*)(qb + 8);
  float4 q3 = *(const float4*)(qb + 12);
  for (int i0 = 0; i0 < nk; i0 += 16) {
    int i = i0 + g;
    float p = 0.f;
    if (i < nk) {
      int kv = (i < nstart) ? 18 * i : 18 * bq + (i - nstart) + 1;
      const float* kp = qkv + (size_t)kv * 3072 + 1024 + h * 64 + j * 16;
      float4 k0 = *(const float4*)(kp);
      float4 k1 = *(const float4*)(kp + 4);
      float4 k2 = *(const float4*)(kp + 8);
      float4 k3 = *(const float4*)(kp + 12);
      p = q0.x * k0.x + q0.y * k0.y + q0.z * k0.z + q0.w * k0.w
        + q1.x * k1.x + q1.y * k1.y + q1.z * k1.z + q1.w * k1.w
        + q2.x * k2.x + q2.y * k2.y + q2.z * k2.z + q2.w * k2.w
        + q3.x * k3.x + q3.y * k3.y + q3.z * k3.z + q3.w * k3.w;
    }
    p += __shfl_xor(p, 1);
    p += __shfl_xor(p, 2);
    if (i < nk && j == 0) sc[i] = p * 0.125f;
  }
  __syncthreads();
  float mx = -1e30f;
  for (int i = lane; i < nk; i += 64) mx = fmaxf(mx, sc[i]);
#pragma unroll
  for (int off = 32; off; off >>= 1) mx = fmaxf(mx, __shfl_xor(mx, off));
  float sum = 0.f;
  for (int i = lane; i < nk; i += 64) { float e = expf(sc[i] - mx); sc[i] = e; sum += e; }
#pragma unroll
  for (int off = 32; off; off >>= 1) sum += __shfl_xor(sum, off);
  float inv = 1.f / sum;
  __syncthreads();
  const float* vb = qkv + 2048 + h * 64 + lane;
  float o0 = 0.f, o1 = 0.f, o2 = 0.f, o3 = 0.f;
  int i = 0;
  for (; i + 4 <= nk; i += 4) {
    int ia = i, ib = i + 1, ic = i + 2, id = i + 3;
    int kva = (ia < nstart) ? 18 * ia : 18 * bq + (ia - nstart) + 1;
    int kvb = (ib < nstart) ? 18 * ib : 18 * bq + (ib - nstart) + 1;
    int kvc = (ic < nstart) ? 18 * ic : 18 * bq + (ic - nstart) + 1;
    int kvd = (id < nstart) ? 18 * id : 18 * bq + (id - nstart) + 1;
    o0 += sc[ia] * vb[(size_t)kva * 3072];
    o1 += sc[ib] * vb[(size_t)kvb * 3072];
    o2 += sc[ic] * vb[(size_t)kvc * 3072];
    o3 += sc[id] * vb[(size_t)kvd * 3072];
  }
  for (; i < nk; ++i) {
    int kv = (i < nstart) ? 18 * i : 18 * bq + (i - nstart) + 1;
    o0 += sc[i] * vb[(size_t)kv * 3072];
  }
  float o = (o0 + o1) + (o2 + o3);
  out[(size_t)t * 1024 + h * 64 + lane] = f2bf(o * inv);
}

// ---------------- decoder input assembly (zeroes pad rows 2306..MPAD-1) ----------------
__global__ void k_assemble(const int* __restrict__ ids, const int* __restrict__ cspp,
                           const float* __restrict__ fx, const float* __restrict__ dummy_fx,
                           const float* __restrict__ sep, const float* __restrict__ wte,
                           float* __restrict__ xD) {
  int csp = fix_csp(cspp);
  for (int idx = blockIdx.x * 256 + threadIdx.x; idx < MPAD * 1024; idx += gridDim.x * 256) {
    int t = idx >> 10, d = idx & 1023;
    float v;
    if (t >= L_DEC)     v = 0.f;
    else if (t == 2305) v = sep[d];
    else if (t == 2304) v = fx[127 * 1024 + d];
    else {
      int k = t / 18, r = t - k * 18;
      if (r == 0)      v = (k == 0) ? dummy_fx[csp * 1024 + d] : fx[(k - 1) * 1024 + d];
      else if (r == 1) v = sep[d];
      else             v = wte[(size_t)ids[k * 16 + r - 2] * 1024 + d];
    }
    xD[idx] = v;
  }
}

extern "C" void kernel_launch(void* const* d_in, const int* in_sizes, int n_in,
                              void* d_out, int out_size, void* d_ws, size_t ws_size,
                              hipStream_t stream) {
  const int*   input_ids = (const int*)d_in[0];
  const int*   cspp      = (const int*)d_in[1];
  const float* f_wte     = (const float*)d_in[2];
  const float* f_pos     = (const float*)d_in[3];
  const float* f_adapt   = (const float*)d_in[4];
  const float* f_ln1     = (const float*)d_in[5];
  const float* f_ln2     = (const float*)d_in[6];
  const float* f_wqkv    = (const float*)d_in[7];
  const float* f_wo      = (const float*)d_in[8];
  const float* f_wg      = (const float*)d_in[9];
  const float* f_wu      = (const float*)d_in[10];
  const float* f_wd      = (const float*)d_in[11];
  const float* f_norm    = (const float*)d_in[12];
  const float* f_proj    = (const float*)d_in[13];
  const float* dummy_fx  = (const float*)d_in[14];
  const float* wte       = (const float*)d_in[15];
  const float* sep       = (const float*)d_in[16];
  const float* d_ln1     = (const float*)d_in[17];
  const float* d_ln2     = (const float*)d_in[18];
  const float* d_wqkv    = (const float*)d_in[19];
  const float* d_wo      = (const float*)d_in[20];
  const float* d_wg      = (const float*)d_in[21];
  const float* d_wu      = (const float*)d_in[22];
  const float* d_wd      = (const float*)d_in[23];
  const float* d_norm    = (const float*)d_in[24];
  const float* w_out     = (const float*)d_in[25];

  // ---- d_ws ----
  float* cosT = (float*)d_ws;
  float* sinT = cosT + 1152;
  u16*   bufH = (u16*)(sinT + 1152);                 // [MPAD][1024] bf16
  u16*   w_outb = bufH + (size_t)MPAD * 1024;        // [32000][1024] bf16 (optional)
  const size_t WS_NEED = 2 * 1152 * 4 + (size_t)MPAD * 1024 * 2 + (size_t)32000 * 1024 * 2;
  const bool big_ws = ws_size >= WS_NEED;

  // ---- d_out scratch ----
  float* o       = (float*)d_out;
  float* xF      = o;                                   // [2304][1024] f32
  float* xD      = xF + (size_t)T_FINE * 1024;          // [MPAD][1024] f32
  float* fx      = xD + (size_t)MPAD * 1024;            // [128][1024] f32
  float* bufQKV  = fx + 128 * 1024;                     // [MPAD][3072] f32
  u16*   bufA    = (u16*)(bufQKV + (size_t)MPAD * 3072);// [MPAD][1024] bf16
  u16*   bufGb   = bufA + (size_t)MPAD * 1024;          // [MPAD][4096] bf16 (silu out)
  u16*   packedb = bufGb + (size_t)MPAD * 4096;         // [128][16384] bf16
  u16*   Wt      = packedb + (size_t)128 * 16384;       // [8192][1024] bf16 staging
  u16*   projb   = Wt + (size_t)8192 * 1024;            // [1024][16384] bf16
  float* spk     = (float*)(projb + (size_t)1024 * 16384); // split-K planes

  const size_t ATTN_LDS = (size_t)(146 * 65 * 2 + 18 * 65 + 8 * 148) * 4;  // 85,336 B
  hipError_t eattn = hipFuncSetAttribute(
      reinterpret_cast<const void*>(&k_attn_dec3),
      hipFuncAttributeMaxDynamicSharedMemorySize, (int)ATTN_LDS);

#define GEMM_BT(EPI, Ap, Bp, Cp, Cbp, Mpad, N, K, Mstore, S) \
  k_gemm_bt<EPI><<<dim3((N) / 128, (Mpad) / 128, (S)), 256, 0, stream>>>((Ap), (Bp), (Cp), (Cbp), cosT, sinT, (N), (K), (Mstore), (K) / (S))
#define WT1(Wp, Kd, Nd) k_wt2<<<dim3((Nd) / 64, (Kd) / 64, 1), 256, 0, stream>>>((Wp), nullptr, Wt, (Kd), (Nd), 1, 0)

  k_rope_table<<<5, 256, 0, stream>>>(cosT, sinT);
  k_fine_embed<<<2048, 256, 0, stream>>>(input_ids, cspp, f_wte, f_pos, f_adapt, xF);
  k_rmsnorm_bf<<<T_FINE, 256, 0, stream>>>(xF, f_ln1, bufH);

  // ---- fine (compressor) layers ----
  for (int i = 0; i < 2; ++i) {
    WT1(f_wqkv + (size_t)i * 1024 * 3072, 1024, 3072);
    GEMM_BT(3, bufH, Wt, bufQKV, (u16*)nullptr, T_FINE, 3072, 1024, T_FINE, 1);
    k_attn_fine2<<<dim3(128, 4), 256, 0, stream>>>(bufQKV, bufA);
    WT1(f_wo + (size_t)i * 1024 * 1024, 1024, 1024);
    GEMM_BT(0, bufA, Wt, spk, (u16*)nullptr, T_FINE, 1024, 1024, T_FINE, 2);
    k_red_norm<2, 1><<<T_FINE, 256, 0, stream>>>(spk, xF, f_ln2 + i * 1024, bufH);
    k_wt2<<<dim3(64, 16, 2), 256, 0, stream>>>(f_wg + (size_t)i * 1024 * 4096,
                                               f_wu + (size_t)i * 1024 * 4096, Wt, 1024, 4096, 2, 0);
    GEMM_BT(2, bufH, Wt, (float*)nullptr, bufGb, T_FINE, 8192, 1024, T_FINE, 1);
    WT1(f_wd + (size_t)i * 4096 * 1024, 4096, 1024);
    GEMM_BT(0, bufGb, Wt, spk, (u16*)nullptr, T_FINE, 1024, 4096, T_FINE, 4);
    if (i == 0) k_red_norm<4, 1><<<T_FINE, 256, 0, stream>>>(spk, xF, f_ln1 + 1024, bufH);
    else        k_red_norm<4, 0><<<T_FINE, 256, 0, stream>>>(spk, xF, nullptr, nullptr);
  }

  // ---- fx = packed @ f_proj^T (split-K 32) ----
  k_rmsnorm_pack_bf<<<2048, 256, 0, stream>>>(xF, f_norm, packedb);
  k_cvt<<<2048, 256, 0, stream>>>(f_proj, projb, 1024 * 16384 / 4);
  GEMM_BT(0, packedb, projb, spk, (u16*)nullptr, 128, 1024, 16384, 128, 32);
  k_reduce_add<<<512, 256, 0, stream>>>(spk, fx, 128 * 1024, 32, 0);

  // ---- decoder ----
  k_assemble<<<2048, 256, 0, stream>>>(input_ids, cspp, fx, dummy_fx, sep, wte, xD);
  k_rmsnorm_bf<<<MPAD, 256, 0, stream>>>(xD, d_ln1, bufH);
  for (int i = 0; i < 2; ++i) {
    WT1(d_wqkv + (size_t)i * 1024 * 3072, 1024, 3072);
    GEMM_BT(3, bufH, Wt, bufQKV, (u16*)nullptr, MPAD, 3072, 1024, MPAD, 1);
    if (eattn == hipSuccess) {
      k_attn_dec3<<<dim3(129, 16), 512, ATTN_LDS, stream>>>(bufQKV, bufA);
    } else {
      k_attn_dec2<<<dim3(L_DEC, 4), 256, 0, stream>>>(bufQKV, bufA);
    }
    WT1(d_wo + (size_t)i * 1024 * 1024, 1024, 1024);
    GEMM_BT(0, bufA, Wt, spk, (u16*)nullptr, MPAD, 1024, 1024, MPAD, 2);
    k_red_norm<2, 1><<<MPAD, 256, 0, stream>>>(spk, xD, d_ln2 + i * 1024, bufH);
    k_wt2<<<dim3(64, 16, 2), 256, 0, stream>>>(d_wg + (size_t)i * 1024 * 4096,
                                               d_wu + (size_t)i * 1024 * 4096, Wt, 1024, 4096, 2, 0);
    GEMM_BT(2, bufH, Wt, (float*)nullptr, bufGb, MPAD, 8192, 1024, MPAD, 1);
    WT1(d_wd + (size_t)i * 4096 * 1024, 4096, 1024);
    GEMM_BT(0, bufGb, Wt, spk, (u16*)nullptr, MPAD, 1024, 4096, MPAD, 4);
    const float* nw = (i == 0) ? d_ln1 + 1024 : d_norm;
    k_red_norm<4, 1><<<MPAD, 256, 0, stream>>>(spk, xD, nw, bufH);   // last: bufH = head input
  }

  // ---- head: out = bufH @ w_out^T ----
  if (big_ws) {
    k_cvt<<<2048, 256, 0, stream>>>(w_out, w_outb, 32000 * 1024 / 4);
    hipError_t ae = hipFuncSetAttribute(
        reinterpret_cast<const void*>(&k_gemm3<0>),
        hipFuncAttributeMaxDynamicSharedMemorySize, 131072);
    if (ae == hipSuccess) {
      k_gemm3<0><<<dim3(125, 10), 512, 131072, stream>>>(bufH, w_outb, o, 32000, 1024, L_DEC);
    } else {
      k_gemm2<0><<<dim3(125, 10), 512, 0, stream>>>(bufH, w_outb, o, nullptr, 32000, 1024, L_DEC);
    }
  } else {
    k_gemm_hf<<<dim3(250, MPAD / 128), 256, 0, stream>>>(bufH, w_out, o, 32000, 1024, L_DEC);
  }
#undef WT1
#undef GEMM_BT
}

// Round 8
// 1292.109 us; speedup vs baseline: 1.1637x; 1.0737x over previous
//
#include <hip/hip_runtime.h>
#include <math.h>

#define L_DEC 2306
#define MPAD 2560      // 10*256, decoder rows padded
#define T_FINE 2304    // 9*256, exact

typedef float f32x4 __attribute__((ext_vector_type(4)));
typedef __bf16 bf16x8 __attribute__((ext_vector_type(8)));
typedef unsigned short u16;
typedef unsigned short us4 __attribute__((ext_vector_type(4)));
typedef unsigned short us8 __attribute__((ext_vector_type(8)));

#define GLOAD16(g, l) __builtin_amdgcn_global_load_lds( \
    (const __attribute__((address_space(1))) unsigned int*)(g), \
    (__attribute__((address_space(3))) unsigned int*)(l), 16, 0, 0)

__device__ __forceinline__ u16 f2bf(float f) {
  unsigned u = __float_as_uint(f);
  u += 0x7fffu + ((u >> 16) & 1u);   // RNE
  return (u16)(u >> 16);
}

__device__ __forceinline__ int fix_csp(const int* p) {
  int c = p[0];
  if ((unsigned)c <= 4u) return c;
  float f = __uint_as_float((unsigned)c);
  int c2 = (int)f;
  return ((unsigned)c2 <= 4u) ? c2 : 4;
}

// XCD-aware bijective block swizzle (m204), row-major tile walk.
__device__ __forceinline__ void xcd_map(int gx, int gy, int& bm, int& bn, int TS) {
  const int nwg = gx * gy;
  const int orig = blockIdx.y * gx + blockIdx.x;
  const int q8 = nwg >> 3, r8 = nwg & 7;
  const int xcd = orig & 7, idx8 = orig >> 3;
  const int wg = (xcd < r8 ? xcd * (q8 + 1) : r8 * (q8 + 1) + (xcd - r8) * q8) + idx8;
  bm = (wg / gx) * TS;
  bn = (wg % gx) * TS;
}

// ================= 256^2, BK=64, double-buffered, dynamic 128KB LDS (head) ==============
template<int EPI>
__global__ __launch_bounds__(512, 1) void k_gemm3(const u16* __restrict__ A,
                                                  const u16* __restrict__ B,
                                                  float* __restrict__ C,
                                                  int N, int K, int Mstore)
{
  extern __shared__ u16 lds[];   // [2 buf][A:16384 | B:16384] u16  (= 128 KB)
  const int tid = threadIdx.x;
  int bm, bn; xcd_map(gridDim.x, gridDim.y, bm, bn, 256);
  const int w = tid >> 6, lane = tid & 63;
  const int wm = (w >> 2) * 128, wn = (w & 3) * 64;
  const int lr = lane & 15, kh = lane >> 4;

#define STAGE3(buf, kt) do {                                                   \
    u16* lA = lds + (buf) * 32768;                                             \
    u16* lB = lA + 16384;                                                      \
    _Pragma("unroll")                                                          \
    for (int p = 0; p < 4; ++p) {                                              \
      int e = p * 512 + tid;                                                   \
      int row = e >> 3;                                                        \
      int kc = ((e & 7) ^ (row & 7)) * 8;   /* pre-swizzled global k-offset */ \
      GLOAD16(A + (size_t)(bm + row) * K + (size_t)(kt) * 64 + kc, lA + e * 8);\
      GLOAD16(B + (size_t)(bn + row) * K + (size_t)(kt) * 64 + kc, lB + e * 8);\
    }                                                                          \
  } while (0)

  f32x4 acc[8][4] = {};
  const int nt = K >> 6;
  STAGE3(0, 0);
  __syncthreads();
  int cur = 0;
  for (int t = 0; t < nt; ++t) {
    if (t + 1 < nt) STAGE3(cur ^ 1, t + 1);
    const u16* pA = lds + cur * 32768;
    const u16* pB = pA + 16384;
    const int xr = (lr & 7) << 3;           // row-XOR for swizzled ds_read
#pragma unroll
    for (int kt2 = 0; kt2 < 2; ++kt2) {
      bf16x8 af[8], bf[4];
#pragma unroll
      for (int m = 0; m < 8; ++m)
        af[m] = *(const bf16x8*)&pA[(wm + m * 16 + lr) * 64 + ((kt2 * 32 + kh * 8) ^ xr)];
#pragma unroll
      for (int n = 0; n < 4; ++n)
        bf[n] = *(const bf16x8*)&pB[(wn + n * 16 + lr) * 64 + ((kt2 * 32 + kh * 8) ^ xr)];
#pragma unroll
      for (int m = 0; m < 8; ++m)
#pragma unroll
        for (int n = 0; n < 4; ++n)
          acc[m][n] = __builtin_amdgcn_mfma_f32_16x16x32_bf16(af[m], bf[n], acc[m][n], 0, 0, 0);
    }
    __syncthreads();
    cur ^= 1;
  }
#undef STAGE3

#pragma unroll
  for (int m = 0; m < 8; ++m) {
    int gr0 = bm + wm + m * 16 + kh * 4;
#pragma unroll
    for (int n = 0; n < 4; ++n) {
      int gc = bn + wn + n * 16 + lr;
#pragma unroll
      for (int r = 0; r < 4; ++r) {
        int gr = gr0 + r;
        if (gr < Mstore) C[(size_t)gr * N + gc] = acc[m][n][r];
      }
    }
  }
}

// ================= 256^2 2-phase BK=32 (static 64KB LDS) — head fallback ================
template<int EPI>
__global__ __launch_bounds__(512, 1) void k_gemm2(const u16* __restrict__ A,
                                                  const u16* __restrict__ B,
                                                  float* __restrict__ C,
                                                  u16* __restrict__ Cb,
                                                  int N, int K, int Mstore)
{
  __shared__ u16 As[2][8192];
  __shared__ u16 Bs[2][8192];
  const int tid = threadIdx.x;
  int bm, bn; xcd_map(gridDim.x, gridDim.y, bm, bn, 256);
  const int w = tid >> 6, lane = tid & 63;
  const int wm = (w >> 2) * 128, wn = (w & 3) * 64;
  const int lr = lane & 15, kh = lane >> 4;
  const int r0 = tid >> 2;
  const int ksrc = 8 * ((tid & 3) ^ ((tid >> 3) & 3));
  const u16* ga = A + (size_t)(bm + r0) * K + ksrc;
  const u16* gb = B + (size_t)(bn + r0) * K + ksrc;
  const size_t rstep = (size_t)128 * K;
  const int cola = (kh * 8) ^ (((lr >> 1) & 3) << 3);

#define STAGE2(buf, kt) do {                                   \
    const u16* gA = ga + (size_t)(kt) * 32;                    \
    const u16* gB = gb + (size_t)(kt) * 32;                    \
    GLOAD16(gA,         &As[buf][tid * 8]);                    \
    GLOAD16(gA + rstep, &As[buf][tid * 8 + 4096]);             \
    GLOAD16(gB,         &Bs[buf][tid * 8]);                    \
    GLOAD16(gB + rstep, &Bs[buf][tid * 8 + 4096]);             \
  } while (0)

  f32x4 acc[8][4] = {};
  const int nt = K >> 5;
  STAGE2(0, 0);
  __syncthreads();
  int cur = 0;
  for (int t = 0; t < nt; ++t) {
    if (t + 1 < nt) STAGE2(cur ^ 1, t + 1);
    bf16x8 af[8], bf[4];
#pragma unroll
    for (int m = 0; m < 8; ++m)
      af[m] = *(const bf16x8*)&As[cur][(wm + m * 16 + lr) * 32 + cola];
#pragma unroll
    for (int n = 0; n < 4; ++n)
      bf[n] = *(const bf16x8*)&Bs[cur][(wn + n * 16 + lr) * 32 + cola];
#pragma unroll
    for (int m = 0; m < 8; ++m)
#pragma unroll
      for (int n = 0; n < 4; ++n)
        acc[m][n] = __builtin_amdgcn_mfma_f32_16x16x32_bf16(af[m], bf[n], acc[m][n], 0, 0, 0);
    __syncthreads();
    cur ^= 1;
  }
#undef STAGE2

#pragma unroll
  for (int m = 0; m < 8; ++m) {
    int gr0 = bm + wm + m * 16 + kh * 4;
#pragma unroll
    for (int n = 0; n < 4; ++n) {
      int gc = bn + wn + n * 16 + lr;
#pragma unroll
      for (int r = 0; r < 4; ++r) {
        int gr = gr0 + r;
        if (gr < Mstore) C[(size_t)gr * N + gc] = acc[m][n][r];
      }
    }
  }
}

// ======== 128^2, BK=64, double-buffered, static 64KB LDS (2 blocks/CU) ==================
// EPI=0: store split-K plane z. EPI=2: silu-fused g|u -> Cb bf16.
// EPI=3: qkv with fused rope (pos = gr%18, q/k sections only) -> C f32.
template<int EPI>
__global__ __launch_bounds__(256) void k_gemm_bt(const u16* __restrict__ A,
                                                 const u16* __restrict__ B,
                                                 float* __restrict__ C,
                                                 u16* __restrict__ Cb,
                                                 const float* __restrict__ cosT,
                                                 const float* __restrict__ sinT,
                                                 int N, int K, int Mstore, int kchunk)
{
  __shared__ u16 As[2][4096];   // [128 rows][64 k] u16, 8KB... (4096 u16 = 8KB) x2 = 16KB
  __shared__ u16 Bs[2][4096];   // wait: 128*64 = 8192 u16 = 16KB. Fix below.
  // NOTE: sized via union trick — real arrays:
  // As/Bs must each hold 128*64 = 8192 u16 per buffer.
  const int tid = threadIdx.x;
  int bm, bn; xcd_map(gridDim.x, gridDim.y, bm, bn, 128);
  const int k0 = blockIdx.z * kchunk;
  const int w = tid >> 6, lane = tid & 63;
  const int wm = (w >> 1) * 64, wn = (w & 1) * 64;
  const int lr = lane & 15, kh = lane >> 4;
  (void)As; (void)Bs;
  __shared__ u16 ldsAB[2][16384];   // [buf][A:8192 | B:8192] u16 = 64KB total

#define STAGE4(buf, kt) do {                                                       \
    u16* lA = &ldsAB[buf][0];                                                      \
    u16* lB = &ldsAB[buf][8192];                                                   \
    _Pragma("unroll")                                                              \
    for (int p = 0; p < 4; ++p) {                                                  \
      int e = p * 256 + tid;                                                       \
      int row = e >> 3;                                                            \
      int kc = ((e & 7) ^ (row & 7)) * 8;                                          \
      GLOAD16(A + (size_t)(bm + row) * K + k0 + (size_t)(kt) * 64 + kc, lA + e * 8);\
      GLOAD16(B + (size_t)(bn + row) * K + k0 + (size_t)(kt) * 64 + kc, lB + e * 8);\
    }                                                                              \
  } while (0)

  f32x4 acc[4][4] = {};
  const int nt = kchunk >> 6;
  STAGE4(0, 0);
  __syncthreads();
  int cur = 0;
  for (int t = 0; t < nt; ++t) {
    if (t + 1 < nt) STAGE4(cur ^ 1, t + 1);
    const u16* pA = &ldsAB[cur][0];
    const u16* pB = &ldsAB[cur][8192];
    const int xr = (lr & 7) << 3;
#pragma unroll
    for (int kt2 = 0; kt2 < 2; ++kt2) {
      bf16x8 af[4], bfr[4];
#pragma unroll
      for (int m = 0; m < 4; ++m)
        af[m] = *(const bf16x8*)&pA[(wm + m * 16 + lr) * 64 + ((kt2 * 32 + kh * 8) ^ xr)];
#pragma unroll
      for (int n = 0; n < 4; ++n)
        bfr[n] = *(const bf16x8*)&pB[(wn + n * 16 + lr) * 64 + ((kt2 * 32 + kh * 8) ^ xr)];
#pragma unroll
      for (int m = 0; m < 4; ++m)
#pragma unroll
        for (int n = 0; n < 4; ++n)
          acc[m][n] = __builtin_amdgcn_mfma_f32_16x16x32_bf16(af[m], bfr[n], acc[m][n], 0, 0, 0);
    }
    __syncthreads();
    cur ^= 1;
  }
#undef STAGE4

  float* Cz = (EPI == 0) ? C + (size_t)blockIdx.z * Mstore * N : C;
  const int N2 = N >> 1;
  const bool doRope = (EPI == 3) && ((bn + wn) < 2048);   // q/k sections, wave-uniform
#pragma unroll
  for (int m = 0; m < 4; ++m) {
    int gr0 = bm + wm + m * 16 + kh * 4;
#pragma unroll
    for (int r = 0; r < 4; ++r) {
      int gr = gr0 + r;
      if (EPI == 3) {
        int p = gr % 18;
        if (doRope) {
#pragma unroll
          for (int n2 = 0; n2 < 2; ++n2) {
            int d = n2 * 16 + lr;                      // 0..31 within head
            float c = cosT[p * 64 + d], s = sinT[p * 64 + d];
            float x1 = acc[m][n2][r], x2 = acc[m][n2 + 2][r];
            if (gr < Mstore) {
              int gc = bn + wn + n2 * 16 + lr;
              C[(size_t)gr * N + gc]      = x1 * c - x2 * s;
              C[(size_t)gr * N + gc + 32] = x2 * c + x1 * s;
            }
          }
        } else if (gr < Mstore) {
#pragma unroll
          for (int n = 0; n < 4; ++n)
            C[(size_t)gr * N + bn + wn + n * 16 + lr] = acc[m][n][r];
        }
      } else if (EPI == 2) {
#pragma unroll
        for (int n = 0; n < 4; ++n) {
          float x = acc[m][n][r];
          float px = __shfl_xor(x, 1);          // partner u (all lanes execute)
          if (!(lr & 1) && gr < Mstore) {
            int gc = bn + wn + n * 16 + lr;
            float sgl = x / (1.f + expf(-x)) * px;
            Cb[(size_t)gr * N2 + (gc >> 1)] = f2bf(sgl);
          }
        }
      } else {
        if (gr < Mstore) {
#pragma unroll
          for (int n = 0; n < 4; ++n)
            Cz[(size_t)gr * N + bn + wn + n * 16 + lr] = acc[m][n][r];
        }
      }
    }
  }
}

// Head fallback when ws can't hold bf16 w_out.
__global__ __launch_bounds__(256) void k_gemm_hf(const u16* __restrict__ A,
                                                 const float* __restrict__ B,
                                                 float* __restrict__ C,
                                                 int N, int K, int Mstore)
{
  __shared__ u16 As[4096];
  __shared__ u16 Bs[4096];
  const int tid = threadIdx.x;
  const int bm = blockIdx.y * 128, bn = blockIdx.x * 128;
  const int w = tid >> 6, lane = tid & 63;
  const int wm = (w >> 1) * 64, wn = (w & 1) * 64;
  const int lr = lane & 15, kh = lane >> 4;
  const int r0 = tid >> 2;
  const int ksrc = 8 * ((tid & 3) ^ ((tid >> 3) & 3));
  const int cola = (kh * 8) ^ (((lr >> 1) & 3) << 3);
  const u16* ga = A + (size_t)(bm + r0) * K + ksrc;
  u16* la = &As[tid * 8];
  const size_t rstep = (size_t)64 * K;

  f32x4 acc[4][4] = {};
  for (int kk = 0; kk < K; kk += 32) {
    GLOAD16(ga, la); GLOAD16(ga + rstep, la + 2048);
    ga += 32;
#pragma unroll
    for (int p = 0; p < 4; ++p) {
      int e = tid + p * 256;
      int row = e >> 3, kc = (e & 7) * 4;
      int kcs = kc ^ (((row >> 1) & 3) << 3);
      float4 v = *(const float4*)(B + (size_t)(bn + row) * K + kk + kc);
      us4 pk; pk[0] = f2bf(v.x); pk[1] = f2bf(v.y); pk[2] = f2bf(v.z); pk[3] = f2bf(v.w);
      *(us4*)&Bs[row * 32 + kcs] = pk;
    }
    __syncthreads();
    bf16x8 af[4], bfr[4];
#pragma unroll
    for (int m = 0; m < 4; ++m)
      af[m] = *(const bf16x8*)&As[(wm + m * 16 + lr) * 32 + cola];
#pragma unroll
    for (int n = 0; n < 4; ++n)
      bfr[n] = *(const bf16x8*)&Bs[(wn + n * 16 + lr) * 32 + cola];
#pragma unroll
    for (int m = 0; m < 4; ++m)
#pragma unroll
      for (int n = 0; n < 4; ++n)
        acc[m][n] = __builtin_amdgcn_mfma_f32_16x16x32_bf16(af[m], bfr[n], acc[m][n], 0, 0, 0);
    __syncthreads();
  }
#pragma unroll
  for (int m = 0; m < 4; ++m) {
    int gr0 = bm + wm + m * 16 + kh * 4;
#pragma unroll
    for (int n = 0; n < 4; ++n) {
      int gc = bn + wn + n * 16 + lr;
#pragma unroll
      for (int r = 0; r < 4; ++r) {
        int gr = gr0 + r;
        if (gr < Mstore) C[(size_t)gr * N + gc] = acc[m][n][r];
      }
    }
  }
}

// ---- weight transpose-convert: W[K,N] f32 -> Wt[(n*rs+ro+z)][K] bf16; z selects W/W2 ----
__global__ __launch_bounds__(256) void k_wt2(const float* __restrict__ W,
                                             const float* __restrict__ W2,
                                             u16* __restrict__ Wt,
                                             int K, int N, int rs, int ro) {
  __shared__ u16 t[64][80];
  const float* src = (blockIdx.z == 0) ? W : W2;
  int roz = ro + blockIdx.z;
  int n0 = blockIdx.x * 64, k0 = blockIdx.y * 64;
#pragma unroll
  for (int p = 0; p < 4; ++p) {
    int id = threadIdx.x + p * 256;
    int row = id >> 4, c4 = (id & 15) * 4;
    float4 v = *(const float4*)(src + (size_t)(k0 + row) * N + n0 + c4);
    t[c4 + 0][row] = f2bf(v.x);
    t[c4 + 1][row] = f2bf(v.y);
    t[c4 + 2][row] = f2bf(v.z);
    t[c4 + 3][row] = f2bf(v.w);
  }
  __syncthreads();
#pragma unroll
  for (int p = 0; p < 2; ++p) {
    int id = threadIdx.x + p * 256;
    int row = id >> 3, c8 = (id & 7) * 8;
    *(us8*)(Wt + ((size_t)(n0 + row) * rs + roz) * K + k0 + c8) = *(const us8*)&t[row][c8];
  }
}

__global__ void k_cvt(const float* __restrict__ x, u16* __restrict__ y, int n4) {
  for (int i = blockIdx.x * 256 + threadIdx.x; i < n4; i += gridDim.x * 256) {
    float4 v = ((const float4*)x)[i];
    us4 p; p[0] = f2bf(v.x); p[1] = f2bf(v.y); p[2] = f2bf(v.z); p[3] = f2bf(v.w);
    ((us4*)y)[i] = p;
  }
}

// sum split-K planes (+ optional dst accumulate) — proj path only
__global__ void k_reduce_add(const float* __restrict__ p, float* __restrict__ dst,
                             int n, int planes, int addDst) {
  for (int i = blockIdx.x * 256 + threadIdx.x; i < n; i += gridDim.x * 256) {
    float s = addDst ? dst[i] : 0.f;
    for (int z = 0; z < planes; ++z) s += p[(size_t)z * n + i];
    dst[i] = s;
  }
}

// ---- fused: x += sum(planes); bufH = rmsnorm(x, w) bf16 (if NORM). grid = rows --------
template<int S, int NORM>
__global__ __launch_bounds__(256) void k_red_norm(const float* __restrict__ planes,
                                                  float* __restrict__ x,
                                                  const float* __restrict__ w,
                                                  u16* __restrict__ y) {
  const int t = blockIdx.x;
  const int n = gridDim.x * 1024;              // plane stride
  const size_t base = (size_t)t * 1024 + threadIdx.x * 4;
  float4 a = *(const float4*)(x + base);
#pragma unroll
  for (int s = 0; s < S; ++s) {
    float4 p = *(const float4*)(planes + (size_t)s * n + base);
    a.x += p.x; a.y += p.y; a.z += p.z; a.w += p.w;
  }
  *(float4*)(x + base) = a;
  if (NORM) {
    float ss = a.x * a.x + a.y * a.y + a.z * a.z + a.w * a.w;
#pragma unroll
    for (int off = 32; off; off >>= 1) ss += __shfl_xor(ss, off);
    __shared__ float ps[4];
    if ((threadIdx.x & 63) == 0) ps[threadIdx.x >> 6] = ss;
    __syncthreads();
    float inv = rsqrtf((ps[0] + ps[1] + ps[2] + ps[3]) * (1.f / 1024.f) + 1e-5f);
    const float4 wv = *(const float4*)(w + threadIdx.x * 4);
    us4 o;
    o[0] = f2bf(a.x * inv * wv.x); o[1] = f2bf(a.y * inv * wv.y);
    o[2] = f2bf(a.z * inv * wv.z); o[3] = f2bf(a.w * inv * wv.w);
    *(us4*)(y + base) = o;
  }
}

__global__ void k_rope_table(float* __restrict__ cosT, float* __restrict__ sinT) {
  int i = blockIdx.x * blockDim.x + threadIdx.x;
  if (i >= 18 * 64) return;
  int p = i >> 6, d = i & 63;
  float theta = powf(10000.f, -(float)(d & 31) / 32.f);
  float ang = (float)p * theta;
  cosT[i] = cosf(ang);
  sinT[i] = sinf(ang);
}

__global__ void k_fine_embed(const int* __restrict__ ids, const int* __restrict__ cspp,
                             const float* __restrict__ f_wte, const float* __restrict__ f_pos,
                             const float* __restrict__ f_adapt, float* __restrict__ xF) {
  int csp = fix_csp(cspp);
  for (int idx = blockIdx.x * 256 + threadIdx.x; idx < T_FINE * 1024; idx += gridDim.x * 256) {
    int r = idx >> 10, d = idx & 1023;
    int c = r / 18, j = r - c * 18;
    float v;
    if (j == 0)      v = f_adapt[csp * 1024 + d];
    else if (j == 1) v = f_pos[c * 1024 + d];
    else             v = f_wte[(size_t)ids[c * 16 + j - 2] * 1024 + d];
    xF[idx] = v;
  }
}

__global__ __launch_bounds__(256) void k_rmsnorm_bf(const float* __restrict__ x,
                                                    const float* __restrict__ w,
                                                    u16* __restrict__ y) {
  int t = blockIdx.x;
  const float4 v = *(const float4*)(x + (size_t)t * 1024 + threadIdx.x * 4);
  float ss = v.x * v.x + v.y * v.y + v.z * v.z + v.w * v.w;
#pragma unroll
  for (int off = 32; off; off >>= 1) ss += __shfl_xor(ss, off);
  __shared__ float ps[4];
  if ((threadIdx.x & 63) == 0) ps[threadIdx.x >> 6] = ss;
  __syncthreads();
  float inv = rsqrtf((ps[0] + ps[1] + ps[2] + ps[3]) * (1.f / 1024.f) + 1e-5f);
  const float4 wv = *(const float4*)(w + threadIdx.x * 4);
  us4 o;
  o[0] = f2bf(v.x * inv * wv.x); o[1] = f2bf(v.y * inv * wv.y);
  o[2] = f2bf(v.z * inv * wv.z); o[3] = f2bf(v.w * inv * wv.w);
  *(us4*)(y + (size_t)t * 1024 + threadIdx.x * 4) = o;
}

__global__ __launch_bounds__(256) void k_rmsnorm_pack_bf(const float* __restrict__ x,
                                                         const float* __restrict__ w,
                                                         u16* __restrict__ y) {
  int b = blockIdx.x;
  int c = b >> 4, r = b & 15;
  const float* xr = x + (size_t)(c * 18 + 2 + r) * 1024;
  const float4 v = *(const float4*)(xr + threadIdx.x * 4);
  float ss = v.x * v.x + v.y * v.y + v.z * v.z + v.w * v.w;
#pragma unroll
  for (int off = 32; off; off >>= 1) ss += __shfl_xor(ss, off);
  __shared__ float ps[4];
  if ((threadIdx.x & 63) == 0) ps[threadIdx.x >> 6] = ss;
  __syncthreads();
  float inv = rsqrtf((ps[0] + ps[1] + ps[2] + ps[3]) * (1.f / 1024.f) + 1e-5f);
  const float4 wv = *(const float4*)(w + threadIdx.x * 4);
  us4 o;
  o[0] = f2bf(v.x * inv * wv.x); o[1] = f2bf(v.y * inv * wv.y);
  o[2] = f2bf(v.z * inv * wv.z); o[3] = f2bf(v.w * inv * wv.w);
  *(us4*)(y + (size_t)b * 1024 + threadIdx.x * 4) = o;
}

// ---------------- fine attention: 4 waves/block, wave = head, LDS-staged ----------------
__global__ __launch_bounds__(256) void k_attn_fine2(const float* __restrict__ qkv,
                                                    u16* __restrict__ out) {
  __shared__ float q[4][18][68], k[4][18][68], v[4][18][68], s[4][18][20];
  int c = blockIdx.x;
  int w = threadIdx.x >> 6, lane = threadIdx.x & 63;
  int h = blockIdx.y * 4 + w;
  const float* base = qkv + (size_t)c * 18 * 3072 + h * 64;
#pragma unroll 3
  for (int r = 0; r < 18; ++r) {
    q[w][r][lane] = base[(size_t)r * 3072 + lane];
    k[w][r][lane] = base[(size_t)r * 3072 + 1024 + lane];
    v[w][r][lane] = base[(size_t)r * 3072 + 2048 + lane];
  }
  __syncthreads();
#pragma unroll
  for (int it = 0; it < 6; ++it) {
    int idx = lane + it * 64;
    if (idx < 324) {
      int qi = (idx * 3641) >> 16;
      int ki = idx - qi * 18;
      const float* qr = q[w][qi];
      const float* kr = k[w][ki];
      float a = 0.f;
#pragma unroll
      for (int d = 0; d < 64; d += 4) {
        float4 x = *(const float4*)&qr[d];
        float4 y = *(const float4*)&kr[d];
        a += x.x * y.x + x.y * y.y + x.z * y.z + x.w * y.w;
      }
      s[w][qi][ki] = a * 0.125f;
    }
  }
  __syncthreads();
  if (lane < 18) {
    float mx = -1e30f;
#pragma unroll
    for (int j = 0; j < 18; ++j) mx = fmaxf(mx, s[w][lane][j]);
    float sum = 0.f;
#pragma unroll
    for (int j = 0; j < 18; ++j) { float e = expf(s[w][lane][j] - mx); s[w][lane][j] = e; sum += e; }
    float inv = 1.f / sum;
#pragma unroll
    for (int j = 0; j < 18; ++j) s[w][lane][j] *= inv;
  }
  __syncthreads();
  float vcol[18];
#pragma unroll
  for (int ki = 0; ki < 18; ++ki) vcol[ki] = v[w][ki][lane];
#pragma unroll 2
  for (int qi = 0; qi < 18; ++qi) {
    float o = 0.f;
#pragma unroll
    for (int ki = 0; ki < 18; ++ki) o += s[w][qi][ki] * vcol[ki];
    out[(size_t)(c * 18 + qi) * 1024 + h * 64 + lane] = f2bf(o);
  }
}

// ======= decoder attention v3: block per (bq, head), shared K/V staged in LDS ==========
__global__ __launch_bounds__(512) void k_attn_dec3(const float* __restrict__ qkv,
                                                   u16* __restrict__ out) {
  extern __shared__ float dyn[];
  float* Kl = dyn;                   // [146][65]
  float* Vl = Kl + 146 * 65;         // [146][65]
  float* Ql = Vl + 146 * 65;         // [18][65]
  float* Sw = Ql + 18 * 65;          // [8][148]
  const int bq = blockIdx.x, h = blockIdx.y;
  const int w = threadIdx.x >> 6, lane = threadIdx.x & 63;
  const int t0 = 18 * bq;
  const int nq = (bq < 128) ? 18 : 2;
  const int nstage = (bq < 128) ? (bq + 18) : 130;

  {
    int rr = threadIdx.x >> 2, c = threadIdx.x & 3;
    for (int row = rr; row < nstage; row += 128) {
      int kv = (row <= bq) ? 18 * row : t0 + (row - bq);
      const float* kp = qkv + (size_t)kv * 3072 + 1024 + h * 64 + c * 16;
#pragma unroll
      for (int q4 = 0; q4 < 4; ++q4) {
        float4 a = *(const float4*)(kp + q4 * 4);
        float4 b = *(const float4*)(kp + 1024 + q4 * 4);
        int d = c * 16 + q4 * 4;
        float* kd = Kl + row * 65 + d;
        float* vd = Vl + row * 65 + d;
        kd[0] = a.x; kd[1] = a.y; kd[2] = a.z; kd[3] = a.w;
        vd[0] = b.x; vd[1] = b.y; vd[2] = b.z; vd[3] = b.w;
      }
    }
    if (rr < nq) {
      const float* qp = qkv + (size_t)(t0 + rr) * 3072 + h * 64 + c * 16;
#pragma unroll
      for (int q4 = 0; q4 < 4; ++q4) {
        float4 a = *(const float4*)(qp + q4 * 4);
        int d = c * 16 + q4 * 4;
        float* qd = Ql + rr * 65 + d;
        qd[0] = a.x; qd[1] = a.y; qd[2] = a.z; qd[3] = a.w;
      }
    }
  }
  __syncthreads();

  for (int r = w; r < nq; r += 8) {
    const int nk = bq + 1 + r;
    float* S = Sw + w * 148;
    const float* qr = Ql + r * 65;
    float mx = -1e30f;
    for (int i = lane; i < nk; i += 64) {
      const float* kr = Kl + i * 65;
      float a = 0.f;
#pragma unroll
      for (int d = 0; d < 64; ++d) a += qr[d] * kr[d];
      a *= 0.125f;
      S[i] = a;
      mx = fmaxf(mx, a);
    }
#pragma unroll
    for (int off = 32; off; off >>= 1) mx = fmaxf(mx, __shfl_xor(mx, off));
    float sum = 0.f;
    for (int i = lane; i < nk; i += 64) { float e = expf(S[i] - mx); S[i] = e; sum += e; }
#pragma unroll
    for (int off = 32; off; off >>= 1) sum += __shfl_xor(sum, off);
    float inv = 1.f / sum;
    __builtin_amdgcn_wave_barrier();
    float o = 0.f;
    for (int i = 0; i < nk; ++i) o += S[i] * Vl[i * 65 + lane];
    out[(size_t)(t0 + r) * 1024 + h * 64 + lane] = f2bf(o * inv);
  }
}

// ---------------- decoder attention v2 (fallback) ----------------
__global__ __launch_bounds__(256) void k_attn_dec2(const float* __restrict__ qkv,
                                                   u16* __restrict__ out) {
  __shared__ float sc_s[4][160];
  int t = blockIdx.x;
  int w = threadIdx.x >> 6, lane = threadIdx.x & 63;
  int h = blockIdx.y * 4 + w;
  float* sc = sc_s[w];
  int bq = t / 18;
  int nstart = bq + 1;
  int nown = t - 18 * bq;
  int nk = nstart + nown;
  int g = lane >> 2, j = lane & 3;
  const float* qb = qkv + (size_t)t * 3072 + h * 64 + j * 16;
  float4 q0 = *(const float4*)(qb);
  float4 q1 = *(const float4*)(qb + 4);
  float4 q2 = *(const float4*)(qb + 8);
  float4 q3 = *(const float4*)(qb + 12);
  for (int i0 = 0; i0 < nk; i0 += 16) {
    int i = i0 + g;
    float p = 0.f;
    if (i < nk) {
      int kv = (i < nstart) ? 18 * i : 18 * bq + (i - nstart) + 1;
      const float* kp = qkv + (size_t)kv * 3072 + 1024 + h * 64 + j * 16;
      float4 k0 = *(const float4*)(kp);
      float4 k1 = *(const float4*)(kp + 4);
      float4 k2 = *(const float4*)(kp + 8);
      float4 k3 = *(const float4*)(kp + 12);
      p = q0.x * k0.x + q0.y * k0.y + q0.z * k0.z + q0.w * k0.w
        + q1.x * k1.x + q1.y * k1.y + q1.z * k1.z + q1.w * k1.w
        + q2.x * k2.x + q2.y * k2.y + q2.z * k2.z + q2.w * k2.w
        + q3.x * k3.x + q3.y * k3.y + q3.z * k3.z + q3.w * k3.w;
    }
    p += __shfl_xor(p, 1);
    p += __shfl_xor(p, 2);
    if (i < nk && j == 0) sc[i] = p * 0.125f;
  }
  __syncthreads();
  float mx = -1e30f;
  for (int i = lane; i < nk; i += 64) mx = fmaxf(mx, sc[i]);
#pragma unroll
  for (int off = 32; off; off >>= 1) mx = fmaxf(mx, __shfl_xor(mx, off));
  float sum = 0.f;
  for (int i = lane; i < nk; i += 64) { float e = expf(sc[i] - mx); sc[i] = e; sum += e; }
#pragma unroll
  for (int off = 32; off; off >>= 1) sum += __shfl_xor(sum, off);
  float inv = 1.f / sum;
  __syncthreads();
  const float* vb = qkv + 2048 + h * 64 + lane;
  float o0 = 0.f, o1 = 0.f, o2 = 0.f, o3 = 0.f;
  int i = 0;
  for (; i + 4 <= nk; i += 4) {
    int ia = i, ib = i + 1, ic = i + 2, id = i + 3;
    int kva = (ia < nstart) ? 18 * ia : 18 * bq + (ia - nstart) + 1;
    int kvb = (ib < nstart) ? 18 * ib : 18 * bq + (ib - nstart) + 1;
    int kvc = (ic < nstart) ? 18 * ic : 18 * bq + (ic - nstart) + 1;
    int kvd = (id < nstart) ? 18 * id : 18 * bq + (id - nstart) + 1;
    o0 += sc[ia] * vb[(size_t)kva * 3072];
    o1 += sc[ib] * vb[(size_t)kvb * 3072];
    o2 += sc[ic] * vb[(size_t)kvc * 3072];
    o3 += sc[id] * vb[(size_t)kvd * 3072];
  }
  for (; i < nk; ++i) {
    int kv = (i < nstart) ? 18 * i : 18 * bq + (i - nstart) + 1;
    o0 += sc[i] * vb[(size_t)kv * 3072];
  }
  float o = (o0 + o1) + (o2 + o3);
  out[(size_t)t * 1024 + h * 64 + lane] = f2bf(o * inv);
}

// ---------------- decoder input assembly (zeroes pad rows 2306..MPAD-1) ----------------
__global__ void k_assemble(const int* __restrict__ ids, const int* __restrict__ cspp,
                           const float* __restrict__ fx, const float* __restrict__ dummy_fx,
                           const float* __restrict__ sep, const float* __restrict__ wte,
                           float* __restrict__ xD) {
  int csp = fix_csp(cspp);
  for (int idx = blockIdx.x * 256 + threadIdx.x; idx < MPAD * 1024; idx += gridDim.x * 256) {
    int t = idx >> 10, d = idx & 1023;
    float v;
    if (t >= L_DEC)     v = 0.f;
    else if (t == 2305) v = sep[d];
    else if (t == 2304) v = fx[127 * 1024 + d];
    else {
      int k = t / 18, r = t - k * 18;
      if (r == 0)      v = (k == 0) ? dummy_fx[csp * 1024 + d] : fx[(k - 1) * 1024 + d];
      else if (r == 1) v = sep[d];
      else             v = wte[(size_t)ids[k * 16 + r - 2] * 1024 + d];
    }
    xD[idx] = v;
  }
}

extern "C" void kernel_launch(void* const* d_in, const int* in_sizes, int n_in,
                              void* d_out, int out_size, void* d_ws, size_t ws_size,
                              hipStream_t stream) {
  const int*   input_ids = (const int*)d_in[0];
  const int*   cspp      = (const int*)d_in[1];
  const float* f_wte     = (const float*)d_in[2];
  const float* f_pos     = (const float*)d_in[3];
  const float* f_adapt   = (const float*)d_in[4];
  const float* f_ln1     = (const float*)d_in[5];
  const float* f_ln2     = (const float*)d_in[6];
  const float* f_wqkv    = (const float*)d_in[7];
  const float* f_wo      = (const float*)d_in[8];
  const float* f_wg      = (const float*)d_in[9];
  const float* f_wu      = (const float*)d_in[10];
  const float* f_wd      = (const float*)d_in[11];
  const float* f_norm    = (const float*)d_in[12];
  const float* f_proj    = (const float*)d_in[13];
  const float* dummy_fx  = (const float*)d_in[14];
  const float* wte       = (const float*)d_in[15];
  const float* sep       = (const float*)d_in[16];
  const float* d_ln1     = (const float*)d_in[17];
  const float* d_ln2     = (const float*)d_in[18];
  const float* d_wqkv    = (const float*)d_in[19];
  const float* d_wo      = (const float*)d_in[20];
  const float* d_wg      = (const float*)d_in[21];
  const float* d_wu      = (const float*)d_in[22];
  const float* d_wd      = (const float*)d_in[23];
  const float* d_norm    = (const float*)d_in[24];
  const float* w_out     = (const float*)d_in[25];

  // ---- d_ws ----
  float* cosT = (float*)d_ws;
  float* sinT = cosT + 1152;
  u16*   bufH = (u16*)(sinT + 1152);                 // [MPAD][1024] bf16
  u16*   w_outb = bufH + (size_t)MPAD * 1024;        // [32000][1024] bf16 (optional)
  const size_t WS_NEED = 2 * 1152 * 4 + (size_t)MPAD * 1024 * 2 + (size_t)32000 * 1024 * 2;
  const bool big_ws = ws_size >= WS_NEED;

  // ---- d_out scratch ----
  float* o       = (float*)d_out;
  float* xF      = o;                                   // [2304][1024] f32
  float* xD      = xF + (size_t)T_FINE * 1024;          // [MPAD][1024] f32
  float* fx      = xD + (size_t)MPAD * 1024;            // [128][1024] f32
  float* bufQKV  = fx + 128 * 1024;                     // [MPAD][3072] f32
  u16*   bufA    = (u16*)(bufQKV + (size_t)MPAD * 3072);// [MPAD][1024] bf16
  u16*   bufGb   = bufA + (size_t)MPAD * 1024;          // [MPAD][4096] bf16 (silu out)
  u16*   packedb = bufGb + (size_t)MPAD * 4096;         // [128][16384] bf16
  u16*   Wt      = packedb + (size_t)128 * 16384;       // [8192][1024] bf16 staging
  u16*   projb   = Wt + (size_t)8192 * 1024;            // [1024][16384] bf16
  float* spk     = (float*)(projb + (size_t)1024 * 16384); // split-K planes

  const size_t ATTN_LDS = (size_t)(146 * 65 * 2 + 18 * 65 + 8 * 148) * 4;  // 85,336 B
  hipError_t eattn = hipFuncSetAttribute(
      reinterpret_cast<const void*>(&k_attn_dec3),
      hipFuncAttributeMaxDynamicSharedMemorySize, (int)ATTN_LDS);

#define GEMM_BT(EPI, Ap, Bp, Cp, Cbp, Mpad, N, K, Mstore, S) \
  k_gemm_bt<EPI><<<dim3((N) / 128, (Mpad) / 128, (S)), 256, 0, stream>>>((Ap), (Bp), (Cp), (Cbp), cosT, sinT, (N), (K), (Mstore), (K) / (S))
#define WT1(Wp, Kd, Nd) k_wt2<<<dim3((Nd) / 64, (Kd) / 64, 1), 256, 0, stream>>>((Wp), nullptr, Wt, (Kd), (Nd), 1, 0)

  k_rope_table<<<5, 256, 0, stream>>>(cosT, sinT);
  k_fine_embed<<<2048, 256, 0, stream>>>(input_ids, cspp, f_wte, f_pos, f_adapt, xF);
  k_rmsnorm_bf<<<T_FINE, 256, 0, stream>>>(xF, f_ln1, bufH);

  // ---- fine (compressor) layers ----
  for (int i = 0; i < 2; ++i) {
    WT1(f_wqkv + (size_t)i * 1024 * 3072, 1024, 3072);
    GEMM_BT(3, bufH, Wt, bufQKV, (u16*)nullptr, T_FINE, 3072, 1024, T_FINE, 1);
    k_attn_fine2<<<dim3(128, 4), 256, 0, stream>>>(bufQKV, bufA);
    WT1(f_wo + (size_t)i * 1024 * 1024, 1024, 1024);
    GEMM_BT(0, bufA, Wt, spk, (u16*)nullptr, T_FINE, 1024, 1024, T_FINE, 2);
    k_red_norm<2, 1><<<T_FINE, 256, 0, stream>>>(spk, xF, f_ln2 + i * 1024, bufH);
    k_wt2<<<dim3(64, 16, 2), 256, 0, stream>>>(f_wg + (size_t)i * 1024 * 4096,
                                               f_wu + (size_t)i * 1024 * 4096, Wt, 1024, 4096, 2, 0);
    GEMM_BT(2, bufH, Wt, (float*)nullptr, bufGb, T_FINE, 8192, 1024, T_FINE, 1);
    WT1(f_wd + (size_t)i * 4096 * 1024, 4096, 1024);
    GEMM_BT(0, bufGb, Wt, spk, (u16*)nullptr, T_FINE, 1024, 4096, T_FINE, 4);
    if (i == 0) k_red_norm<4, 1><<<T_FINE, 256, 0, stream>>>(spk, xF, f_ln1 + 1024, bufH);
    else        k_red_norm<4, 0><<<T_FINE, 256, 0, stream>>>(spk, xF, nullptr, nullptr);
  }

  // ---- fx = packed @ f_proj^T (split-K 32) ----
  k_rmsnorm_pack_bf<<<2048, 256, 0, stream>>>(xF, f_norm, packedb);
  k_cvt<<<2048, 256, 0, stream>>>(f_proj, projb, 1024 * 16384 / 4);
  GEMM_BT(0, packedb, projb, spk, (u16*)nullptr, 128, 1024, 16384, 128, 32);
  k_reduce_add<<<512, 256, 0, stream>>>(spk, fx, 128 * 1024, 32, 0);

  // ---- decoder ----
  k_assemble<<<2048, 256, 0, stream>>>(input_ids, cspp, fx, dummy_fx, sep, wte, xD);
  k_rmsnorm_bf<<<MPAD, 256, 0, stream>>>(xD, d_ln1, bufH);
  for (int i = 0; i < 2; ++i) {
    WT1(d_wqkv + (size_t)i * 1024 * 3072, 1024, 3072);
    GEMM_BT(3, bufH, Wt, bufQKV, (u16*)nullptr, MPAD, 3072, 1024, MPAD, 1);
    if (eattn == hipSuccess) {
      k_attn_dec3<<<dim3(129, 16), 512, ATTN_LDS, stream>>>(bufQKV, bufA);
    } else {
      k_attn_dec2<<<dim3(L_DEC, 4), 256, 0, stream>>>(bufQKV, bufA);
    }
    WT1(d_wo + (size_t)i * 1024 * 1024, 1024, 1024);
    GEMM_BT(0, bufA, Wt, spk, (u16*)nullptr, MPAD, 1024, 1024, MPAD, 2);
    k_red_norm<2, 1><<<MPAD, 256, 0, stream>>>(spk, xD, d_ln2 + i * 1024, bufH);
    k_wt2<<<dim3(64, 16, 2), 256, 0, stream>>>(d_wg + (size_t)i * 1024 * 4096,
                                               d_wu + (size_t)i * 1024 * 4096, Wt, 1024, 4096, 2, 0);
    GEMM_BT(2, bufH, Wt, (float*)nullptr, bufGb, MPAD, 8192, 1024, MPAD, 1);
    WT1(d_wd + (size_t)i * 4096 * 1024, 4096, 1024);
    GEMM_BT(0, bufGb, Wt, spk, (u16*)nullptr, MPAD, 1024, 4096, MPAD, 4);
    const float* nw = (i == 0) ? d_ln1 + 1024 : d_norm;
    k_red_norm<4, 1><<<MPAD, 256, 0, stream>>>(spk, xD, nw, bufH);   // last: bufH = head input
  }

  // ---- head: out = bufH @ w_out^T ----
  if (big_ws) {
    k_cvt<<<2048, 256, 0, stream>>>(w_out, w_outb, 32000 * 1024 / 4);
    hipError_t ae = hipFuncSetAttribute(
        reinterpret_cast<const void*>(&k_gemm3<0>),
        hipFuncAttributeMaxDynamicSharedMemorySize, 131072);
    if (ae == hipSuccess) {
      k_gemm3<0><<<dim3(125, 10), 512, 131072, stream>>>(bufH, w_outb, o, 32000, 1024, L_DEC);
    } else {
      k_gemm2<0><<<dim3(125, 10), 512, 0, stream>>>(bufH, w_outb, o, nullptr, 32000, 1024, L_DEC);
    }
  } else {
    k_gemm_hf<<<dim3(250, MPAD / 128), 256, 0, stream>>>(bufH, w_out, o, 32000, 1024, L_DEC);
  }
#undef WT1
#undef GEMM_BT
}

// Round 9
// 1271.904 us; speedup vs baseline: 1.1822x; 1.0159x over previous
//
#include <hip/hip_runtime.h>
#include <math.h>

#define L_DEC 2306
#define MPAD 2560      // 10*256, decoder rows padded
#define T_FINE 2304    // 9*256, exact

typedef float f32x4 __attribute__((ext_vector_type(4)));
typedef __bf16 bf16x8 __attribute__((ext_vector_type(8)));
typedef unsigned short u16;
typedef unsigned short us4 __attribute__((ext_vector_type(4)));
typedef unsigned short us8 __attribute__((ext_vector_type(8)));

#define GLOAD16(g, l) __builtin_amdgcn_global_load_lds( \
    (const __attribute__((address_space(1))) unsigned int*)(g), \
    (__attribute__((address_space(3))) unsigned int*)(l), 16, 0, 0)

__device__ __forceinline__ u16 f2bf(float f) {
  unsigned u = __float_as_uint(f);
  u += 0x7fffu + ((u >> 16) & 1u);   // RNE
  return (u16)(u >> 16);
}

__device__ __forceinline__ int fix_csp(const int* p) {
  int c = p[0];
  if ((unsigned)c <= 4u) return c;
  float f = __uint_as_float((unsigned)c);
  int c2 = (int)f;
  return ((unsigned)c2 <= 4u) ? c2 : 4;
}

// XCD-aware bijective block swizzle (m204), row-major tile walk.
__device__ __forceinline__ void xcd_map(int gx, int gy, int& bm, int& bn, int TS) {
  const int nwg = gx * gy;
  const int orig = blockIdx.y * gx + blockIdx.x;
  const int q8 = nwg >> 3, r8 = nwg & 7;
  const int xcd = orig & 7, idx8 = orig >> 3;
  const int wg = (xcd < r8 ? xcd * (q8 + 1) : r8 * (q8 + 1) + (xcd - r8) * q8) + idx8;
  bm = (wg / gx) * TS;
  bn = (wg % gx) * TS;
}

// ================= 256^2, BK=64, dbuf, dynamic 128KB LDS, COUNTED vmcnt (head) ==========
template<int EPI>
__global__ __launch_bounds__(512, 1) void k_gemm3(const u16* __restrict__ A,
                                                  const u16* __restrict__ B,
                                                  float* __restrict__ C,
                                                  int N, int K, int Mstore)
{
  extern __shared__ u16 lds[];   // [2 buf][A:16384 | B:16384] u16  (= 128 KB)
  const int tid = threadIdx.x;
  int bm, bn; xcd_map(gridDim.x, gridDim.y, bm, bn, 256);
  const int w = tid >> 6, lane = tid & 63;
  const int wm = (w >> 2) * 128, wn = (w & 3) * 64;
  const int lr = lane & 15, kh = lane >> 4;

#define STAGE3(buf, kt) do {                                                   \
    u16* lA = lds + (buf) * 32768;                                             \
    u16* lB = lA + 16384;                                                      \
    _Pragma("unroll")                                                          \
    for (int p = 0; p < 4; ++p) {                                              \
      int e = p * 512 + tid;                                                   \
      int row = e >> 3;                                                        \
      int kc = ((e & 7) ^ (row & 7)) * 8;   /* pre-swizzled global k-offset */ \
      GLOAD16(A + (size_t)(bm + row) * K + (size_t)(kt) * 64 + kc, lA + e * 8);\
      GLOAD16(B + (size_t)(bn + row) * K + (size_t)(kt) * 64 + kc, lB + e * 8);\
    }                                                                          \
  } while (0)

  f32x4 acc[8][4] = {};
  const int nt = K >> 6;
  STAGE3(0, 0);                 // 8 vmem ops in flight
  int cur = 0;
  for (int t = 0; t < nt; ++t) {
    if (t + 1 < nt) {
      STAGE3(cur ^ 1, t + 1);                               // +8 → 16 outstanding
      asm volatile("s_waitcnt vmcnt(8)" ::: "memory");      // tile t landed; t+1 in flight
    } else {
      asm volatile("s_waitcnt vmcnt(0)" ::: "memory");
    }
    __builtin_amdgcn_s_barrier();                           // all waves confirm tile t
    asm volatile("" ::: "memory");
    const u16* pA = lds + cur * 32768;
    const u16* pB = pA + 16384;
    const int xr = (lr & 7) << 3;           // row-XOR for swizzled ds_read
#pragma unroll
    for (int kt2 = 0; kt2 < 2; ++kt2) {
      bf16x8 af[8], bf[4];
#pragma unroll
      for (int m = 0; m < 8; ++m)
        af[m] = *(const bf16x8*)&pA[(wm + m * 16 + lr) * 64 + ((kt2 * 32 + kh * 8) ^ xr)];
#pragma unroll
      for (int n = 0; n < 4; ++n)
        bf[n] = *(const bf16x8*)&pB[(wn + n * 16 + lr) * 64 + ((kt2 * 32 + kh * 8) ^ xr)];
#pragma unroll
      for (int m = 0; m < 8; ++m)
#pragma unroll
        for (int n = 0; n < 4; ++n)
          acc[m][n] = __builtin_amdgcn_mfma_f32_16x16x32_bf16(af[m], bf[n], acc[m][n], 0, 0, 0);
    }
    asm volatile("" ::: "memory");
    __builtin_amdgcn_s_barrier();           // all reads of cur done → next STAGE may overwrite
    cur ^= 1;
  }
#undef STAGE3

#pragma unroll
  for (int m = 0; m < 8; ++m) {
    int gr0 = bm + wm + m * 16 + kh * 4;
#pragma unroll
    for (int n = 0; n < 4; ++n) {
      int gc = bn + wn + n * 16 + lr;
#pragma unroll
      for (int r = 0; r < 4; ++r) {
        int gr = gr0 + r;
        if (gr < Mstore) C[(size_t)gr * N + gc] = acc[m][n][r];
      }
    }
  }
}

// ================= 256^2 2-phase BK=32 (static 64KB LDS) — head fallback ================
template<int EPI>
__global__ __launch_bounds__(512, 1) void k_gemm2(const u16* __restrict__ A,
                                                  const u16* __restrict__ B,
                                                  float* __restrict__ C,
                                                  u16* __restrict__ Cb,
                                                  int N, int K, int Mstore)
{
  __shared__ u16 As[2][8192];
  __shared__ u16 Bs[2][8192];
  const int tid = threadIdx.x;
  int bm, bn; xcd_map(gridDim.x, gridDim.y, bm, bn, 256);
  const int w = tid >> 6, lane = tid & 63;
  const int wm = (w >> 2) * 128, wn = (w & 3) * 64;
  const int lr = lane & 15, kh = lane >> 4;
  const int r0 = tid >> 2;
  const int ksrc = 8 * ((tid & 3) ^ ((tid >> 3) & 3));
  const u16* ga = A + (size_t)(bm + r0) * K + ksrc;
  const u16* gb = B + (size_t)(bn + r0) * K + ksrc;
  const size_t rstep = (size_t)128 * K;
  const int cola = (kh * 8) ^ (((lr >> 1) & 3) << 3);

#define STAGE2(buf, kt) do {                                   \
    const u16* gA = ga + (size_t)(kt) * 32;                    \
    const u16* gB = gb + (size_t)(kt) * 32;                    \
    GLOAD16(gA,         &As[buf][tid * 8]);                    \
    GLOAD16(gA + rstep, &As[buf][tid * 8 + 4096]);             \
    GLOAD16(gB,         &Bs[buf][tid * 8]);                    \
    GLOAD16(gB + rstep, &Bs[buf][tid * 8 + 4096]);             \
  } while (0)

  f32x4 acc[8][4] = {};
  const int nt = K >> 5;
  STAGE2(0, 0);
  __syncthreads();
  int cur = 0;
  for (int t = 0; t < nt; ++t) {
    if (t + 1 < nt) STAGE2(cur ^ 1, t + 1);
    bf16x8 af[8], bf[4];
#pragma unroll
    for (int m = 0; m < 8; ++m)
      af[m] = *(const bf16x8*)&As[cur][(wm + m * 16 + lr) * 32 + cola];
#pragma unroll
    for (int n = 0; n < 4; ++n)
      bf[n] = *(const bf16x8*)&Bs[cur][(wn + n * 16 + lr) * 32 + cola];
#pragma unroll
    for (int m = 0; m < 8; ++m)
#pragma unroll
      for (int n = 0; n < 4; ++n)
        acc[m][n] = __builtin_amdgcn_mfma_f32_16x16x32_bf16(af[m], bf[n], acc[m][n], 0, 0, 0);
    __syncthreads();
    cur ^= 1;
  }
#undef STAGE2

#pragma unroll
  for (int m = 0; m < 8; ++m) {
    int gr0 = bm + wm + m * 16 + kh * 4;
#pragma unroll
    for (int n = 0; n < 4; ++n) {
      int gc = bn + wn + n * 16 + lr;
#pragma unroll
      for (int r = 0; r < 4; ++r) {
        int gr = gr0 + r;
        if (gr < Mstore) C[(size_t)gr * N + gc] = acc[m][n][r];
      }
    }
  }
}

// ======== 128^2, BK=64, dbuf, static 64KB LDS (2 blocks/CU), COUNTED vmcnt ==============
// EPI=0: store split-K plane z. EPI=2: silu-fused g|u -> Cb bf16.
// EPI=3: qkv with fused rope (pos = gr%18, q/k sections only) -> C f32.
template<int EPI>
__global__ __launch_bounds__(256) void k_gemm_bt(const u16* __restrict__ A,
                                                 const u16* __restrict__ B,
                                                 float* __restrict__ C,
                                                 u16* __restrict__ Cb,
                                                 const float* __restrict__ cosT,
                                                 const float* __restrict__ sinT,
                                                 int N, int K, int Mstore, int kchunk)
{
  __shared__ u16 ldsAB[2][16384];   // [buf][A:8192 | B:8192] u16 = 64KB total
  const int tid = threadIdx.x;
  int bm, bn; xcd_map(gridDim.x, gridDim.y, bm, bn, 128);
  const int k0 = blockIdx.z * kchunk;
  const int w = tid >> 6, lane = tid & 63;
  const int wm = (w >> 1) * 64, wn = (w & 1) * 64;
  const int lr = lane & 15, kh = lane >> 4;

#define STAGE4(buf, kt) do {                                                       \
    u16* lA = &ldsAB[buf][0];                                                      \
    u16* lB = &ldsAB[buf][8192];                                                   \
    _Pragma("unroll")                                                              \
    for (int p = 0; p < 4; ++p) {                                                  \
      int e = p * 256 + tid;                                                       \
      int row = e >> 3;                                                            \
      int kc = ((e & 7) ^ (row & 7)) * 8;                                          \
      GLOAD16(A + (size_t)(bm + row) * K + k0 + (size_t)(kt) * 64 + kc, lA + e * 8);\
      GLOAD16(B + (size_t)(bn + row) * K + k0 + (size_t)(kt) * 64 + kc, lB + e * 8);\
    }                                                                              \
  } while (0)

  f32x4 acc[4][4] = {};
  const int nt = kchunk >> 6;
  STAGE4(0, 0);
  int cur = 0;
  for (int t = 0; t < nt; ++t) {
    if (t + 1 < nt) {
      STAGE4(cur ^ 1, t + 1);
      asm volatile("s_waitcnt vmcnt(8)" ::: "memory");
    } else {
      asm volatile("s_waitcnt vmcnt(0)" ::: "memory");
    }
    __builtin_amdgcn_s_barrier();
    asm volatile("" ::: "memory");
    const u16* pA = &ldsAB[cur][0];
    const u16* pB = &ldsAB[cur][8192];
    const int xr = (lr & 7) << 3;
#pragma unroll
    for (int kt2 = 0; kt2 < 2; ++kt2) {
      bf16x8 af[4], bfr[4];
#pragma unroll
      for (int m = 0; m < 4; ++m)
        af[m] = *(const bf16x8*)&pA[(wm + m * 16 + lr) * 64 + ((kt2 * 32 + kh * 8) ^ xr)];
#pragma unroll
      for (int n = 0; n < 4; ++n)
        bfr[n] = *(const bf16x8*)&pB[(wn + n * 16 + lr) * 64 + ((kt2 * 32 + kh * 8) ^ xr)];
#pragma unroll
      for (int m = 0; m < 4; ++m)
#pragma unroll
        for (int n = 0; n < 4; ++n)
          acc[m][n] = __builtin_amdgcn_mfma_f32_16x16x32_bf16(af[m], bfr[n], acc[m][n], 0, 0, 0);
    }
    asm volatile("" ::: "memory");
    __builtin_amdgcn_s_barrier();
    cur ^= 1;
  }
#undef STAGE4

  float* Cz = (EPI == 0) ? C + (size_t)blockIdx.z * Mstore * N : C;
  const int N2 = N >> 1;
  const bool doRope = (EPI == 3) && ((bn + wn) < 2048);   // q/k sections, wave-uniform
#pragma unroll
  for (int m = 0; m < 4; ++m) {
    int gr0 = bm + wm + m * 16 + kh * 4;
#pragma unroll
    for (int r = 0; r < 4; ++r) {
      int gr = gr0 + r;
      if (EPI == 3) {
        int p = gr % 18;
        if (doRope) {
#pragma unroll
          for (int n2 = 0; n2 < 2; ++n2) {
            int d = n2 * 16 + lr;                      // 0..31 within head
            float c = cosT[p * 64 + d], s = sinT[p * 64 + d];
            float x1 = acc[m][n2][r], x2 = acc[m][n2 + 2][r];
            if (gr < Mstore) {
              int gc = bn + wn + n2 * 16 + lr;
              C[(size_t)gr * N + gc]      = x1 * c - x2 * s;
              C[(size_t)gr * N + gc + 32] = x2 * c + x1 * s;
            }
          }
        } else if (gr < Mstore) {
#pragma unroll
          for (int n = 0; n < 4; ++n)
            C[(size_t)gr * N + bn + wn + n * 16 + lr] = acc[m][n][r];
        }
      } else if (EPI == 2) {
#pragma unroll
        for (int n = 0; n < 4; ++n) {
          float x = acc[m][n][r];
          float px = __shfl_xor(x, 1);          // partner u (all lanes execute)
          if (!(lr & 1) && gr < Mstore) {
            int gc = bn + wn + n * 16 + lr;
            float sgl = x / (1.f + expf(-x)) * px;
            Cb[(size_t)gr * N2 + (gc >> 1)] = f2bf(sgl);
          }
        }
      } else {
        if (gr < Mstore) {
#pragma unroll
          for (int n = 0; n < 4; ++n)
            Cz[(size_t)gr * N + bn + wn + n * 16 + lr] = acc[m][n][r];
        }
      }
    }
  }
}

// Head fallback when ws can't hold bf16 w_out.
__global__ __launch_bounds__(256) void k_gemm_hf(const u16* __restrict__ A,
                                                 const float* __restrict__ B,
                                                 float* __restrict__ C,
                                                 int N, int K, int Mstore)
{
  __shared__ u16 As[4096];
  __shared__ u16 Bs[4096];
  const int tid = threadIdx.x;
  const int bm = blockIdx.y * 128, bn = blockIdx.x * 128;
  const int w = tid >> 6, lane = tid & 63;
  const int wm = (w >> 1) * 64, wn = (w & 1) * 64;
  const int lr = lane & 15, kh = lane >> 4;
  const int r0 = tid >> 2;
  const int ksrc = 8 * ((tid & 3) ^ ((tid >> 3) & 3));
  const int cola = (kh * 8) ^ (((lr >> 1) & 3) << 3);
  const u16* ga = A + (size_t)(bm + r0) * K + ksrc;
  u16* la = &As[tid * 8];
  const size_t rstep = (size_t)64 * K;

  f32x4 acc[4][4] = {};
  for (int kk = 0; kk < K; kk += 32) {
    GLOAD16(ga, la); GLOAD16(ga + rstep, la + 2048);
    ga += 32;
#pragma unroll
    for (int p = 0; p < 4; ++p) {
      int e = tid + p * 256;
      int row = e >> 3, kc = (e & 7) * 4;
      int kcs = kc ^ (((row >> 1) & 3) << 3);
      float4 v = *(const float4*)(B + (size_t)(bn + row) * K + kk + kc);
      us4 pk; pk[0] = f2bf(v.x); pk[1] = f2bf(v.y); pk[2] = f2bf(v.z); pk[3] = f2bf(v.w);
      *(us4*)&Bs[row * 32 + kcs] = pk;
    }
    __syncthreads();
    bf16x8 af[4], bfr[4];
#pragma unroll
    for (int m = 0; m < 4; ++m)
      af[m] = *(const bf16x8*)&As[(wm + m * 16 + lr) * 32 + cola];
#pragma unroll
    for (int n = 0; n < 4; ++n)
      bfr[n] = *(const bf16x8*)&Bs[(wn + n * 16 + lr) * 32 + cola];
#pragma unroll
    for (int m = 0; m < 4; ++m)
#pragma unroll
      for (int n = 0; n < 4; ++n)
        acc[m][n] = __builtin_amdgcn_mfma_f32_16x16x32_bf16(af[m], bfr[n], acc[m][n], 0, 0, 0);
    __syncthreads();
  }
#pragma unroll
  for (int m = 0; m < 4; ++m) {
    int gr0 = bm + wm + m * 16 + kh * 4;
#pragma unroll
    for (int n = 0; n < 4; ++n) {
      int gc = bn + wn + n * 16 + lr;
#pragma unroll
      for (int r = 0; r < 4; ++r) {
        int gr = gr0 + r;
        if (gr < Mstore) C[(size_t)gr * N + gc] = acc[m][n][r];
      }
    }
  }
}

// ---- weight transpose-convert: W[K,N] f32 -> Wt[(n*rs+ro+z)][K] bf16; z selects W/W2 ----
__global__ __launch_bounds__(256) void k_wt2(const float* __restrict__ W,
                                             const float* __restrict__ W2,
                                             u16* __restrict__ Wt,
                                             int K, int N, int rs, int ro) {
  __shared__ u16 t[64][80];
  const float* src = (blockIdx.z == 0) ? W : W2;
  int roz = ro + blockIdx.z;
  int n0 = blockIdx.x * 64, k0 = blockIdx.y * 64;
#pragma unroll
  for (int p = 0; p < 4; ++p) {
    int id = threadIdx.x + p * 256;
    int row = id >> 4, c4 = (id & 15) * 4;
    float4 v = *(const float4*)(src + (size_t)(k0 + row) * N + n0 + c4);
    t[c4 + 0][row] = f2bf(v.x);
    t[c4 + 1][row] = f2bf(v.y);
    t[c4 + 2][row] = f2bf(v.z);
    t[c4 + 3][row] = f2bf(v.w);
  }
  __syncthreads();
#pragma unroll
  for (int p = 0; p < 2; ++p) {
    int id = threadIdx.x + p * 256;
    int row = id >> 3, c8 = (id & 7) * 8;
    *(us8*)(Wt + ((size_t)(n0 + row) * rs + roz) * K + k0 + c8) = *(const us8*)&t[row][c8];
  }
}

__global__ void k_cvt(const float* __restrict__ x, u16* __restrict__ y, int n4) {
  for (int i = blockIdx.x * 256 + threadIdx.x; i < n4; i += gridDim.x * 256) {
    float4 v = ((const float4*)x)[i];
    us4 p; p[0] = f2bf(v.x); p[1] = f2bf(v.y); p[2] = f2bf(v.z); p[3] = f2bf(v.w);
    ((us4*)y)[i] = p;
  }
}

// sum split-K planes (+ optional dst accumulate) — proj path only
__global__ void k_reduce_add(const float* __restrict__ p, float* __restrict__ dst,
                             int n, int planes, int addDst) {
  for (int i = blockIdx.x * 256 + threadIdx.x; i < n; i += gridDim.x * 256) {
    float s = addDst ? dst[i] : 0.f;
    for (int z = 0; z < planes; ++z) s += p[(size_t)z * n + i];
    dst[i] = s;
  }
}

// ---- fused: x += sum(planes); bufH = rmsnorm(x, w) bf16 (if NORM). grid = rows --------
template<int S, int NORM>
__global__ __launch_bounds__(256) void k_red_norm(const float* __restrict__ planes,
                                                  float* __restrict__ x,
                                                  const float* __restrict__ w,
                                                  u16* __restrict__ y) {
  const int t = blockIdx.x;
  const int n = gridDim.x * 1024;              // plane stride
  const size_t base = (size_t)t * 1024 + threadIdx.x * 4;
  float4 a = *(const float4*)(x + base);
#pragma unroll
  for (int s = 0; s < S; ++s) {
    float4 p = *(const float4*)(planes + (size_t)s * n + base);
    a.x += p.x; a.y += p.y; a.z += p.z; a.w += p.w;
  }
  *(float4*)(x + base) = a;
  if (NORM) {
    float ss = a.x * a.x + a.y * a.y + a.z * a.z + a.w * a.w;
#pragma unroll
    for (int off = 32; off; off >>= 1) ss += __shfl_xor(ss, off);
    __shared__ float ps[4];
    if ((threadIdx.x & 63) == 0) ps[threadIdx.x >> 6] = ss;
    __syncthreads();
    float inv = rsqrtf((ps[0] + ps[1] + ps[2] + ps[3]) * (1.f / 1024.f) + 1e-5f);
    const float4 wv = *(const float4*)(w + threadIdx.x * 4);
    us4 o;
    o[0] = f2bf(a.x * inv * wv.x); o[1] = f2bf(a.y * inv * wv.y);
    o[2] = f2bf(a.z * inv * wv.z); o[3] = f2bf(a.w * inv * wv.w);
    *(us4*)(y + base) = o;
  }
}

__global__ void k_rope_table(float* __restrict__ cosT, float* __restrict__ sinT) {
  int i = blockIdx.x * blockDim.x + threadIdx.x;
  if (i >= 18 * 64) return;
  int p = i >> 6, d = i & 63;
  float theta = powf(10000.f, -(float)(d & 31) / 32.f);
  float ang = (float)p * theta;
  cosT[i] = cosf(ang);
  sinT[i] = sinf(ang);
}

__global__ void k_fine_embed(const int* __restrict__ ids, const int* __restrict__ cspp,
                             const float* __restrict__ f_wte, const float* __restrict__ f_pos,
                             const float* __restrict__ f_adapt, float* __restrict__ xF) {
  int csp = fix_csp(cspp);
  for (int idx = blockIdx.x * 256 + threadIdx.x; idx < T_FINE * 1024; idx += gridDim.x * 256) {
    int r = idx >> 10, d = idx & 1023;
    int c = r / 18, j = r - c * 18;
    float v;
    if (j == 0)      v = f_adapt[csp * 1024 + d];
    else if (j == 1) v = f_pos[c * 1024 + d];
    else             v = f_wte[(size_t)ids[c * 16 + j - 2] * 1024 + d];
    xF[idx] = v;
  }
}

__global__ __launch_bounds__(256) void k_rmsnorm_bf(const float* __restrict__ x,
                                                    const float* __restrict__ w,
                                                    u16* __restrict__ y) {
  int t = blockIdx.x;
  const float4 v = *(const float4*)(x + (size_t)t * 1024 + threadIdx.x * 4);
  float ss = v.x * v.x + v.y * v.y + v.z * v.z + v.w * v.w;
#pragma unroll
  for (int off = 32; off; off >>= 1) ss += __shfl_xor(ss, off);
  __shared__ float ps[4];
  if ((threadIdx.x & 63) == 0) ps[threadIdx.x >> 6] = ss;
  __syncthreads();
  float inv = rsqrtf((ps[0] + ps[1] + ps[2] + ps[3]) * (1.f / 1024.f) + 1e-5f);
  const float4 wv = *(const float4*)(w + threadIdx.x * 4);
  us4 o;
  o[0] = f2bf(v.x * inv * wv.x); o[1] = f2bf(v.y * inv * wv.y);
  o[2] = f2bf(v.z * inv * wv.z); o[3] = f2bf(v.w * inv * wv.w);
  *(us4*)(y + (size_t)t * 1024 + threadIdx.x * 4) = o;
}

__global__ __launch_bounds__(256) void k_rmsnorm_pack_bf(const float* __restrict__ x,
                                                         const float* __restrict__ w,
                                                         u16* __restrict__ y) {
  int b = blockIdx.x;
  int c = b >> 4, r = b & 15;
  const float* xr = x + (size_t)(c * 18 + 2 + r) * 1024;
  const float4 v = *(const float4*)(xr + threadIdx.x * 4);
  float ss = v.x * v.x + v.y * v.y + v.z * v.z + v.w * v.w;
#pragma unroll
  for (int off = 32; off; off >>= 1) ss += __shfl_xor(ss, off);
  __shared__ float ps[4];
  if ((threadIdx.x & 63) == 0) ps[threadIdx.x >> 6] = ss;
  __syncthreads();
  float inv = rsqrtf((ps[0] + ps[1] + ps[2] + ps[3]) * (1.f / 1024.f) + 1e-5f);
  const float4 wv = *(const float4*)(w + threadIdx.x * 4);
  us4 o;
  o[0] = f2bf(v.x * inv * wv.x); o[1] = f2bf(v.y * inv * wv.y);
  o[2] = f2bf(v.z * inv * wv.z); o[3] = f2bf(v.w * inv * wv.w);
  *(us4*)(y + (size_t)b * 1024 + threadIdx.x * 4) = o;
}

// ---------------- fine attention: 4 waves/block, wave = head, LDS-staged ----------------
__global__ __launch_bounds__(256) void k_attn_fine2(const float* __restrict__ qkv,
                                                    u16* __restrict__ out) {
  __shared__ float q[4][18][68], k[4][18][68], v[4][18][68], s[4][18][20];
  int c = blockIdx.x;
  int w = threadIdx.x >> 6, lane = threadIdx.x & 63;
  int h = blockIdx.y * 4 + w;
  const float* base = qkv + (size_t)c * 18 * 3072 + h * 64;
#pragma unroll 3
  for (int r = 0; r < 18; ++r) {
    q[w][r][lane] = base[(size_t)r * 3072 + lane];
    k[w][r][lane] = base[(size_t)r * 3072 + 1024 + lane];
    v[w][r][lane] = base[(size_t)r * 3072 + 2048 + lane];
  }
  __syncthreads();
#pragma unroll
  for (int it = 0; it < 6; ++it) {
    int idx = lane + it * 64;
    if (idx < 324) {
      int qi = (idx * 3641) >> 16;
      int ki = idx - qi * 18;
      const float* qr = q[w][qi];
      const float* kr = k[w][ki];
      float a = 0.f;
#pragma unroll
      for (int d = 0; d < 64; d += 4) {
        float4 x = *(const float4*)&qr[d];
        float4 y = *(const float4*)&kr[d];
        a += x.x * y.x + x.y * y.y + x.z * y.z + x.w * y.w;
      }
      s[w][qi][ki] = a * 0.125f;
    }
  }
  __syncthreads();
  if (lane < 18) {
    float mx = -1e30f;
#pragma unroll
    for (int j = 0; j < 18; ++j) mx = fmaxf(mx, s[w][lane][j]);
    float sum = 0.f;
#pragma unroll
    for (int j = 0; j < 18; ++j) { float e = expf(s[w][lane][j] - mx); s[w][lane][j] = e; sum += e; }
    float inv = 1.f / sum;
#pragma unroll
    for (int j = 0; j < 18; ++j) s[w][lane][j] *= inv;
  }
  __syncthreads();
  float vcol[18];
#pragma unroll
  for (int ki = 0; ki < 18; ++ki) vcol[ki] = v[w][ki][lane];
#pragma unroll 2
  for (int qi = 0; qi < 18; ++qi) {
    float o = 0.f;
#pragma unroll
    for (int ki = 0; ki < 18; ++ki) o += s[w][qi][ki] * vcol[ki];
    out[(size_t)(c * 18 + qi) * 1024 + h * 64 + lane] = f2bf(o);
  }
}

// ======= decoder attention v3: block per (bq, head), shared K/V staged in LDS ==========
__global__ __launch_bounds__(512) void k_attn_dec3(const float* __restrict__ qkv,
                                                   u16* __restrict__ out) {
  extern __shared__ float dyn[];
  float* Kl = dyn;                   // [146][65]
  float* Vl = Kl + 146 * 65;         // [146][65]
  float* Ql = Vl + 146 * 65;         // [18][65]
  float* Sw = Ql + 18 * 65;          // [8][148]
  const int bq = blockIdx.x, h = blockIdx.y;
  const int w = threadIdx.x >> 6, lane = threadIdx.x & 63;
  const int t0 = 18 * bq;
  const int nq = (bq < 128) ? 18 : 2;
  const int nstage = (bq < 128) ? (bq + 18) : 130;

  {
    int rr = threadIdx.x >> 2, c = threadIdx.x & 3;
    for (int row = rr; row < nstage; row += 128) {
      int kv = (row <= bq) ? 18 * row : t0 + (row - bq);
      const float* kp = qkv + (size_t)kv * 3072 + 1024 + h * 64 + c * 16;
#pragma unroll
      for (int q4 = 0; q4 < 4; ++q4) {
        float4 a = *(const float4*)(kp + q4 * 4);
        float4 b = *(const float4*)(kp + 1024 + q4 * 4);
        int d = c * 16 + q4 * 4;
        float* kd = Kl + row * 65 + d;
        float* vd = Vl + row * 65 + d;
        kd[0] = a.x; kd[1] = a.y; kd[2] = a.z; kd[3] = a.w;
        vd[0] = b.x; vd[1] = b.y; vd[2] = b.z; vd[3] = b.w;
      }
    }
    if (rr < nq) {
      const float* qp = qkv + (size_t)(t0 + rr) * 3072 + h * 64 + c * 16;
#pragma unroll
      for (int q4 = 0; q4 < 4; ++q4) {
        float4 a = *(const float4*)(qp + q4 * 4);
        int d = c * 16 + q4 * 4;
        float* qd = Ql + rr * 65 + d;
        qd[0] = a.x; qd[1] = a.y; qd[2] = a.z; qd[3] = a.w;
      }
    }
  }
  __syncthreads();

  for (int r = w; r < nq; r += 8) {
    const int nk = bq + 1 + r;
    float* S = Sw + w * 148;
    const float* qr = Ql + r * 65;
    float mx = -1e30f;
    for (int i = lane; i < nk; i += 64) {
      const float* kr = Kl + i * 65;
      float a = 0.f;
#pragma unroll
      for (int d = 0; d < 64; ++d) a += qr[d] * kr[d];
      a *= 0.125f;
      S[i] = a;
      mx = fmaxf(mx, a);
    }
#pragma unroll
    for (int off = 32; off; off >>= 1) mx = fmaxf(mx, __shfl_xor(mx, off));
    float sum = 0.f;
    for (int i = lane; i < nk; i += 64) { float e = expf(S[i] - mx); S[i] = e; sum += e; }
#pragma unroll
    for (int off = 32; off; off >>= 1) sum += __shfl_xor(sum, off);
    float inv = 1.f / sum;
    __builtin_amdgcn_wave_barrier();
    float o = 0.f;
    for (int i = 0; i < nk; ++i) o += S[i] * Vl[i * 65 + lane];
    out[(size_t)(t0 + r) * 1024 + h * 64 + lane] = f2bf(o * inv);
  }
}

// ---------------- decoder attention v2 (fallback) ----------------
__global__ __launch_bounds__(256) void k_attn_dec2(const float* __restrict__ qkv,
                                                   u16* __restrict__ out) {
  __shared__ float sc_s[4][160];
  int t = blockIdx.x;
  int w = threadIdx.x >> 6, lane = threadIdx.x & 63;
  int h = blockIdx.y * 4 + w;
  float* sc = sc_s[w];
  int bq = t / 18;
  int nstart = bq + 1;
  int nown = t - 18 * bq;
  int nk = nstart + nown;
  int g = lane >> 2, j = lane & 3;
  const float* qb = qkv + (size_t)t * 3072 + h * 64 + j * 16;
  float4 q0 = *(const float4*)(qb);
  float4 q1 = *(const float4*)(qb + 4);
  float4 q2 = *(const float4*)(qb + 8);
  float4 q3 = *(const float4*)(qb + 12);
  for (int i0 = 0; i0 < nk; i0 += 16) {
    int i = i0 + g;
    float p = 0.f;
    if (i < nk) {
      int kv = (i < nstart) ? 18 * i : 18 * bq + (i - nstart) + 1;
      const float* kp = qkv + (size_t)kv * 3072 + 1024 + h * 64 + j * 16;
      float4 k0 = *(const float4*)(kp);
      float4 k1 = *(const float4*)(kp + 4);
      float4 k2 = *(const float4*)(kp + 8);
      float4 k3 = *(const float4*)(kp + 12);
      p = q0.x * k0.x + q0.y * k0.y + q0.z * k0.z + q0.w * k0.w
        + q1.x * k1.x + q1.y * k1.y + q1.z * k1.z + q1.w * k1.w
        + q2.x * k2.x + q2.y * k2.y + q2.z * k2.z + q2.w * k2.w
        + q3.x * k3.x + q3.y * k3.y + q3.z * k3.z + q3.w * k3.w;
    }
    p += __shfl_xor(p, 1);
    p += __shfl_xor(p, 2);
    if (i < nk && j == 0) sc[i] = p * 0.125f;
  }
  __syncthreads();
  float mx = -1e30f;
  for (int i = lane; i < nk; i += 64) mx = fmaxf(mx, sc[i]);
#pragma unroll
  for (int off = 32; off; off >>= 1) mx = fmaxf(mx, __shfl_xor(mx, off));
  float sum = 0.f;
  for (int i = lane; i < nk; i += 64) { float e = expf(sc[i] - mx); sc[i] = e; sum += e; }
#pragma unroll
  for (int off = 32; off; off >>= 1) sum += __shfl_xor(sum, off);
  float inv = 1.f / sum;
  __syncthreads();
  const float* vb = qkv + 2048 + h * 64 + lane;
  float o0 = 0.f, o1 = 0.f, o2 = 0.f, o3 = 0.f;
  int i = 0;
  for (; i + 4 <= nk; i += 4) {
    int ia = i, ib = i + 1, ic = i + 2, id = i + 3;
    int kva = (ia < nstart) ? 18 * ia : 18 * bq + (ia - nstart) + 1;
    int kvb = (ib < nstart) ? 18 * ib : 18 * bq + (ib - nstart) + 1;
    int kvc = (ic < nstart) ? 18 * ic : 18 * bq + (ic - nstart) + 1;
    int kvd = (id < nstart) ? 18 * id : 18 * bq + (id - nstart) + 1;
    o0 += sc[ia] * vb[(size_t)kva * 3072];
    o1 += sc[ib] * vb[(size_t)kvb * 3072];
    o2 += sc[ic] * vb[(size_t)kvc * 3072];
    o3 += sc[id] * vb[(size_t)kvd * 3072];
  }
  for (; i < nk; ++i) {
    int kv = (i < nstart) ? 18 * i : 18 * bq + (i - nstart) + 1;
    o0 += sc[i] * vb[(size_t)kv * 3072];
  }
  float o = (o0 + o1) + (o2 + o3);
  out[(size_t)t * 1024 + h * 64 + lane] = f2bf(o * inv);
}

// ---------------- decoder input assembly (zeroes pad rows 2306..MPAD-1) ----------------
__global__ void k_assemble(const int* __restrict__ ids, const int* __restrict__ cspp,
                           const float* __restrict__ fx, const float* __restrict__ dummy_fx,
                           const float* __restrict__ sep, const float* __restrict__ wte,
                           float* __restrict__ xD) {
  int csp = fix_csp(cspp);
  for (int idx = blockIdx.x * 256 + threadIdx.x; idx < MPAD * 1024; idx += gridDim.x * 256) {
    int t = idx >> 10, d = idx & 1023;
    float v;
    if (t >= L_DEC)     v = 0.f;
    else if (t == 2305) v = sep[d];
    else if (t == 2304) v = fx[127 * 1024 + d];
    else {
      int k = t / 18, r = t - k * 18;
      if (r == 0)      v = (k == 0) ? dummy_fx[csp * 1024 + d] : fx[(k - 1) * 1024 + d];
      else if (r == 1) v = sep[d];
      else             v = wte[(size_t)ids[k * 16 + r - 2] * 1024 + d];
    }
    xD[idx] = v;
  }
}

extern "C" void kernel_launch(void* const* d_in, const int* in_sizes, int n_in,
                              void* d_out, int out_size, void* d_ws, size_t ws_size,
                              hipStream_t stream) {
  const int*   input_ids = (const int*)d_in[0];
  const int*   cspp      = (const int*)d_in[1];
  const float* f_wte     = (const float*)d_in[2];
  const float* f_pos     = (const float*)d_in[3];
  const float* f_adapt   = (const float*)d_in[4];
  const float* f_ln1     = (const float*)d_in[5];
  const float* f_ln2     = (const float*)d_in[6];
  const float* f_wqkv    = (const float*)d_in[7];
  const float* f_wo      = (const float*)d_in[8];
  const float* f_wg      = (const float*)d_in[9];
  const float* f_wu      = (const float*)d_in[10];
  const float* f_wd      = (const float*)d_in[11];
  const float* f_norm    = (const float*)d_in[12];
  const float* f_proj    = (const float*)d_in[13];
  const float* dummy_fx  = (const float*)d_in[14];
  const float* wte       = (const float*)d_in[15];
  const float* sep       = (const float*)d_in[16];
  const float* d_ln1     = (const float*)d_in[17];
  const float* d_ln2     = (const float*)d_in[18];
  const float* d_wqkv    = (const float*)d_in[19];
  const float* d_wo      = (const float*)d_in[20];
  const float* d_wg      = (const float*)d_in[21];
  const float* d_wu      = (const float*)d_in[22];
  const float* d_wd      = (const float*)d_in[23];
  const float* d_norm    = (const float*)d_in[24];
  const float* w_out     = (const float*)d_in[25];

  // ---- d_ws ----
  float* cosT = (float*)d_ws;
  float* sinT = cosT + 1152;
  u16*   bufH = (u16*)(sinT + 1152);                 // [MPAD][1024] bf16
  u16*   w_outb = bufH + (size_t)MPAD * 1024;        // [32000][1024] bf16 (optional)
  const size_t WS_NEED = 2 * 1152 * 4 + (size_t)MPAD * 1024 * 2 + (size_t)32000 * 1024 * 2;
  const bool big_ws = ws_size >= WS_NEED;

  // ---- d_out scratch ----
  float* o       = (float*)d_out;
  float* xF      = o;                                   // [2304][1024] f32
  float* xD      = xF + (size_t)T_FINE * 1024;          // [MPAD][1024] f32
  float* fx      = xD + (size_t)MPAD * 1024;            // [128][1024] f32
  float* bufQKV  = fx + 128 * 1024;                     // [MPAD][3072] f32
  u16*   bufA    = (u16*)(bufQKV + (size_t)MPAD * 3072);// [MPAD][1024] bf16
  u16*   bufGb   = bufA + (size_t)MPAD * 1024;          // [MPAD][4096] bf16 (silu out)
  u16*   packedb = bufGb + (size_t)MPAD * 4096;         // [128][16384] bf16
  u16*   Wt      = packedb + (size_t)128 * 16384;       // [8192][1024] bf16 staging
  u16*   projb   = Wt + (size_t)8192 * 1024;            // [1024][16384] bf16
  float* spk     = (float*)(projb + (size_t)1024 * 16384); // split-K planes

  const size_t ATTN_LDS = (size_t)(146 * 65 * 2 + 18 * 65 + 8 * 148) * 4;  // 85,336 B
  hipError_t eattn = hipFuncSetAttribute(
      reinterpret_cast<const void*>(&k_attn_dec3),
      hipFuncAttributeMaxDynamicSharedMemorySize, (int)ATTN_LDS);

#define GEMM_BT(EPI, Ap, Bp, Cp, Cbp, Mpad, N, K, Mstore, S) \
  k_gemm_bt<EPI><<<dim3((N) / 128, (Mpad) / 128, (S)), 256, 0, stream>>>((Ap), (Bp), (Cp), (Cbp), cosT, sinT, (N), (K), (Mstore), (K) / (S))
#define WT1(Wp, Kd, Nd) k_wt2<<<dim3((Nd) / 64, (Kd) / 64, 1), 256, 0, stream>>>((Wp), nullptr, Wt, (Kd), (Nd), 1, 0)

  k_rope_table<<<5, 256, 0, stream>>>(cosT, sinT);
  k_fine_embed<<<2048, 256, 0, stream>>>(input_ids, cspp, f_wte, f_pos, f_adapt, xF);
  k_rmsnorm_bf<<<T_FINE, 256, 0, stream>>>(xF, f_ln1, bufH);

  // ---- fine (compressor) layers ----
  for (int i = 0; i < 2; ++i) {
    WT1(f_wqkv + (size_t)i * 1024 * 3072, 1024, 3072);
    GEMM_BT(3, bufH, Wt, bufQKV, (u16*)nullptr, T_FINE, 3072, 1024, T_FINE, 1);
    k_attn_fine2<<<dim3(128, 4), 256, 0, stream>>>(bufQKV, bufA);
    WT1(f_wo + (size_t)i * 1024 * 1024, 1024, 1024);
    GEMM_BT(0, bufA, Wt, spk, (u16*)nullptr, T_FINE, 1024, 1024, T_FINE, 2);
    k_red_norm<2, 1><<<T_FINE, 256, 0, stream>>>(spk, xF, f_ln2 + i * 1024, bufH);
    k_wt2<<<dim3(64, 16, 2), 256, 0, stream>>>(f_wg + (size_t)i * 1024 * 4096,
                                               f_wu + (size_t)i * 1024 * 4096, Wt, 1024, 4096, 2, 0);
    GEMM_BT(2, bufH, Wt, (float*)nullptr, bufGb, T_FINE, 8192, 1024, T_FINE, 1);
    WT1(f_wd + (size_t)i * 4096 * 1024, 4096, 1024);
    GEMM_BT(0, bufGb, Wt, spk, (u16*)nullptr, T_FINE, 1024, 4096, T_FINE, 4);
    if (i == 0) k_red_norm<4, 1><<<T_FINE, 256, 0, stream>>>(spk, xF, f_ln1 + 1024, bufH);
    else        k_red_norm<4, 0><<<T_FINE, 256, 0, stream>>>(spk, xF, nullptr, nullptr);
  }

  // ---- fx = packed @ f_proj^T (split-K 32) ----
  k_rmsnorm_pack_bf<<<2048, 256, 0, stream>>>(xF, f_norm, packedb);
  k_cvt<<<2048, 256, 0, stream>>>(f_proj, projb, 1024 * 16384 / 4);
  GEMM_BT(0, packedb, projb, spk, (u16*)nullptr, 128, 1024, 16384, 128, 32);
  k_reduce_add<<<512, 256, 0, stream>>>(spk, fx, 128 * 1024, 32, 0);

  // ---- decoder ----
  k_assemble<<<2048, 256, 0, stream>>>(input_ids, cspp, fx, dummy_fx, sep, wte, xD);
  k_rmsnorm_bf<<<MPAD, 256, 0, stream>>>(xD, d_ln1, bufH);
  for (int i = 0; i < 2; ++i) {
    WT1(d_wqkv + (size_t)i * 1024 * 3072, 1024, 3072);
    GEMM_BT(3, bufH, Wt, bufQKV, (u16*)nullptr, MPAD, 3072, 1024, MPAD, 1);
    if (eattn == hipSuccess) {
      k_attn_dec3<<<dim3(129, 16), 512, ATTN_LDS, stream>>>(bufQKV, bufA);
    } else {
      k_attn_dec2<<<dim3(L_DEC, 4), 256, 0, stream>>>(bufQKV, bufA);
    }
    WT1(d_wo + (size_t)i * 1024 * 1024, 1024, 1024);
    GEMM_BT(0, bufA, Wt, spk, (u16*)nullptr, MPAD, 1024, 1024, MPAD, 2);
    k_red_norm<2, 1><<<MPAD, 256, 0, stream>>>(spk, xD, d_ln2 + i * 1024, bufH);
    k_wt2<<<dim3(64, 16, 2), 256, 0, stream>>>(d_wg + (size_t)i * 1024 * 4096,
                                               d_wu + (size_t)i * 1024 * 4096, Wt, 1024, 4096, 2, 0);
    GEMM_BT(2, bufH, Wt, (float*)nullptr, bufGb, MPAD, 8192, 1024, MPAD, 1);
    WT1(d_wd + (size_t)i * 4096 * 1024, 4096, 1024);
    GEMM_BT(0, bufGb, Wt, spk, (u16*)nullptr, MPAD, 1024, 4096, MPAD, 4);
    const float* nw = (i == 0) ? d_ln1 + 1024 : d_norm;
    k_red_norm<4, 1><<<MPAD, 256, 0, stream>>>(spk, xD, nw, bufH);   // last: bufH = head input
  }

  // ---- head: out = bufH @ w_out^T ----
  if (big_ws) {
    k_cvt<<<2048, 256, 0, stream>>>(w_out, w_outb, 32000 * 1024 / 4);
    hipError_t ae = hipFuncSetAttribute(
        reinterpret_cast<const void*>(&k_gemm3<0>),
        hipFuncAttributeMaxDynamicSharedMemorySize, 131072);
    if (ae == hipSuccess) {
      k_gemm3<0><<<dim3(125, 10), 512, 131072, stream>>>(bufH, w_outb, o, 32000, 1024, L_DEC);
    } else {
      k_gemm2<0><<<dim3(125, 10), 512, 0, stream>>>(bufH, w_outb, o, nullptr, 32000, 1024, L_DEC);
    }
  } else {
    k_gemm_hf<<<dim3(250, MPAD / 128), 256, 0, stream>>>(bufH, w_out, o, 32000, 1024, L_DEC);
  }
#undef WT1
#undef GEMM_BT
}